// Round 10
// baseline (3694.229 us; speedup 1.0000x reference)
//
#include <hip/hip_runtime.h>
#include <hip/hip_bf16.h>

typedef __hip_bfloat16 bf16;
typedef __attribute__((ext_vector_type(8))) __bf16 bf16x8;
typedef __attribute__((ext_vector_type(4))) float f32x4;

#define N_NODES 32768
#define N_EDGES 262144
#define DIM 768
#define NGR 64
#define KIN 800     // 784 padded to 32
#define KSTACK 6912 // self(768) + 8*768
#define NKEY (N_NODES * 8)

#define GLOBAL_AS __attribute__((address_space(1)))
#define LDS_AS __attribute__((address_space(3)))

__device__ __forceinline__ float gelu_f(float x) {
    return 0.5f * x * (1.0f + erff(x * 0.70710678118654752f));
}
__device__ __forceinline__ float bfu(unsigned short v) {
    union { unsigned u; float f; } x; x.u = (unsigned)v << 16; return x.f;
}
__device__ __forceinline__ unsigned short fbf(float f) {
    bf16 t = __float2bfloat16(f); return *(unsigned short*)&t;
}

// ---------------------------------------------------------------------------
// Transpose + cast fp32 [I][O] -> bf16 [O][ostride], zero-pad i in [I,Ipad)
__global__ __launch_bounds__(256)
void tcast_k(const float* __restrict__ in, bf16* __restrict__ out, int I, int O,
             int Ipad, int ostride) {
    __shared__ float t[32][33];
    const int i0 = blockIdx.x * 32, o0 = blockIdx.y * 32;
    const int tx = threadIdx.x & 31, ty = threadIdx.x >> 5;
#pragma unroll
    for (int q = 0; q < 4; ++q) {
        int i = i0 + ty + q * 8, o = o0 + tx;
        t[ty + q * 8][tx] = (i < I) ? in[(size_t)i * O + o] : 0.0f;
    }
    __syncthreads();
#pragma unroll
    for (int q = 0; q < 4; ++q) {
        int o = o0 + ty + q * 8, i = i0 + tx;
        if (i < Ipad) out[(size_t)o * ostride + i] = __float2bfloat16(t[tx][ty + q * 8]);
    }
}

// ---------------------------------------------------------------------------
// RGCN weights -> Wst[l][768 out][6912 K], K order: [self | r0..r7]. grid(24,24,27)
__global__ __launch_bounds__(256)
void wprep_k(const float* __restrict__ W_rel, const float* __restrict__ W_loop,
             bf16* __restrict__ Wst) {
    __shared__ float t[32][33];
    const int z = blockIdx.z, l = z / 9, q = z % 9;
    const float* in = (q < 8) ? W_rel + ((size_t)(l * 8 + q)) * DIM * DIM
                              : W_loop + (size_t)l * DIM * DIM;
    bf16* out = Wst + (size_t)l * DIM * KSTACK + (q < 8 ? (q + 1) * DIM : 0);
    const int i0 = blockIdx.x * 32, o0 = blockIdx.y * 32;
    const int tx = threadIdx.x & 31, ty = threadIdx.x >> 5;
#pragma unroll
    for (int qq = 0; qq < 4; ++qq)
        t[ty + qq * 8][tx] = in[(size_t)(i0 + ty + qq * 8) * DIM + o0 + tx];
    __syncthreads();
#pragma unroll
    for (int qq = 0; qq < 4; ++qq)
        out[(size_t)(o0 + ty + qq * 8) * KSTACK + i0 + tx] =
            __float2bfloat16(t[tx][ty + qq * 8]);
}

// ---------------------------------------------------------------------------
__global__ __launch_bounds__(256)
void concat_k(const float* __restrict__ tv, const float* __restrict__ cv, bf16* __restrict__ X) {
    const int n = blockIdx.x;
    for (int c = threadIdx.x; c < KIN; c += 256) {
        float v = 0.0f;
        if (c < 16) v = tv[(size_t)n * 16 + c];
        else if (c < 784) v = cv[(size_t)n * DIM + (c - 16)];
        X[(size_t)n * KIN + c] = __float2bfloat16(v);
    }
}

// ---------------------------------------------------------------------------
// CSR build over key = dst*8 + type
__global__ __launch_bounds__(256)
void hist2_k(const int* __restrict__ dst, const int* __restrict__ et, int* __restrict__ deg) {
    int e = blockIdx.x * 256 + threadIdx.x;
    if (e < N_EDGES) atomicAdd(&deg[dst[e] * 8 + et[e]], 1);
}

__global__ __launch_bounds__(1024)
void scan2_k(const int* __restrict__ deg, int* __restrict__ rp, int* __restrict__ cur) {
    __shared__ int part[1024];
    const int t = threadIdx.x;
    const int base_i = t * 256;
    int s = 0;
    for (int i = 0; i < 256; ++i) s += deg[base_i + i];
    part[t] = s; __syncthreads();
    for (int st = 1; st < 1024; st <<= 1) {
        int v = (t >= st) ? part[t - st] : 0;
        __syncthreads();
        part[t] += v;
        __syncthreads();
    }
    int run = part[t] - s;
    for (int i = 0; i < 256; ++i) {
        int d = deg[base_i + i];
        rp[base_i + i] = run; cur[base_i + i] = run;
        run += d;
    }
    if (t == 1023) rp[NKEY] = run;
}

__global__ __launch_bounds__(256)
void place2_k(const int* __restrict__ src, const int* __restrict__ dst,
              const int* __restrict__ et, int* __restrict__ cur, int* __restrict__ eidx) {
    int e = blockIdx.x * 256 + threadIdx.x;
    if (e >= N_EDGES) return;
    int pos = atomicAdd(&cur[dst[e] * 8 + et[e]], 1);
    eidx[pos] = src[e];
}

// ---------------------------------------------------------------------------
// Gather-aggregate for NC relations [rbase, rbase+NC), exact CSR ranges.
template <int NC>
__global__ __launch_bounds__(256)
void gather2_k(const bf16* __restrict__ h, const int* __restrict__ rp2,
               const int* __restrict__ eidx, bf16* __restrict__ AGG, int rbase) {
    const int wave = threadIdx.x >> 6, lane = threadIdx.x & 63;
    const int n = blockIdx.x * 4 + wave;
    const int c0 = 2 * lane;
    unsigned short* outrow = (unsigned short*)&AGG[(size_t)n * (NC * DIM)];
    const int* bp = &rp2[n * 8 + rbase];
#pragma unroll 1
    for (int sel = 0; sel < NC; ++sel) {
        const int s = bp[sel], e = bp[sel + 1];
        float2 f[6] = {};
        for (int t = s; t < e; ++t) {
            const unsigned short* hs = (const unsigned short*)&h[(size_t)eidx[t] * DIM];
#pragma unroll
            for (int j = 0; j < 6; ++j) {
                ushort2 u = *(const ushort2*)&hs[c0 + j * 128];
                f[j].x += bfu(u.x); f[j].y += bfu(u.y);
            }
        }
#pragma unroll
        for (int j = 0; j < 6; ++j) {
            ushort2 o; o.x = fbf(f[j].x); o.y = fbf(f[j].y);
            *(ushort2*)&outrow[sel * DIM + c0 + j * 128] = o;
        }
    }
}

// ---------------------------------------------------------------------------
// gemm_bl2: C[M,Nn](f32) (+)= A[M,K] @ BT[Nn,K]^T. BM=128, BN=256, BK=32.
// KEY CHANGE vs all prior rounds: B fragments are loaded DIRECTLY from global
// (L2-resident weight panel, <=4.7MB) into VGPRs -- B never touches LDS.
// LDS stages only the 8KB A-tile. This raises FLOP per LDS-byte from ~43 to
// ~87, taking the LDS read pipe (the measured ~85-128 B/cy wall that pinned
// rounds 3-9 at 20-25% MfmaUtil) off the critical path.
// 512 thr = 8 waves (2 row x 4 col), sync 2-barrier loop, round-8-proven
// 0-conflict A swizzle (src chunk s^((r>>1)&3), read chunk lg^((l15>>1)&3)).
// (512,4): 16 waves/CU (4/SIMD) to hide L2 latency on B loads; VGPR 120<=128.
template <int ACCUM>
__global__ __launch_bounds__(512, 4)
void gemm_bl2(const bf16* __restrict__ A1, int S1, int K1,
              const bf16* __restrict__ A2, int S2,
              const bf16* __restrict__ BT, int ldb,
              float* __restrict__ OUT, int Nn, int Ktot, int nbx) {
    __shared__ __align__(16) unsigned short lA[128 * 32];   // 8 KB
    const int nblk = gridDim.x, qx = nblk >> 3, bid = blockIdx.x;
    const int wgid = (bid & 7) * qx + (bid >> 3);           // XCD-chunked swizzle
    const int bx = wgid % nbx, by = wgid / nbx;
    const int bn = bx * 256, bm = by * 128;
    const int tid = threadIdx.x;
    const int wave = tid >> 6, lane = tid & 63;
    const int wr = wave >> 2, wc = wave & 3;
    const int l15 = lane & 15, lg = lane >> 4;

    // per-lane B row pointers (4 fragments, fixed rows; advance by k)
    const bf16* bp0 = BT + (size_t)(bn + wc * 64 +  0 + l15) * ldb + lg * 8;
    const bf16* bp1 = BT + (size_t)(bn + wc * 64 + 16 + l15) * ldb + lg * 8;
    const bf16* bp2 = BT + (size_t)(bn + wc * 64 + 32 + l15) * ldb + lg * 8;
    const bf16* bp3 = BT + (size_t)(bn + wc * 64 + 48 + l15) * ldb + lg * 8;

    f32x4 acc[4][4] = {};
    const int nkt = Ktot >> 5;

    for (int kt = 0; kt < nkt; ++kt) {
        const int kbase = kt * 32;
        // --- B fragments: direct global (L2) loads, no LDS
        bf16x8 bq0 = *(const bf16x8*)(bp0 + kbase);
        bf16x8 bq1 = *(const bf16x8*)(bp1 + kbase);
        bf16x8 bq2 = *(const bf16x8*)(bp2 + kbase);
        bf16x8 bq3 = *(const bf16x8*)(bp3 + kbase);
        // --- A tile: 128x32 = 512 16B chunks, 1 per thread, swizzled source
        {
            const bf16* Ab; int stA, koff;
            if (kbase < K1) { Ab = A1; stA = S1; koff = kbase; }
            else            { Ab = A2; stA = S2; koff = kbase - K1; }
            const int r = tid >> 2, s = tid & 3;
            const int sc = (s ^ ((r >> 1) & 3)) * 8;
            const bf16* ga = Ab + (size_t)(bm + r) * stA + koff + sc;
            __builtin_amdgcn_global_load_lds((const GLOBAL_AS void*)ga,
                (LDS_AS void*)&lA[tid * 8], 16, 0, 0);
        }
        __syncthreads();

        bf16x8 af[4];
#pragma unroll
        for (int mi = 0; mi < 4; ++mi) {
            const int r = wr * 64 + mi * 16 + l15;
            const int p = (lg ^ ((l15 >> 1) & 3)) * 8;
            af[mi] = *(const bf16x8*)&lA[r * 32 + p];
        }
#pragma unroll
        for (int mi = 0; mi < 4; ++mi) {
            acc[mi][0] = __builtin_amdgcn_mfma_f32_16x16x32_bf16(af[mi], bq0, acc[mi][0], 0, 0, 0);
            acc[mi][1] = __builtin_amdgcn_mfma_f32_16x16x32_bf16(af[mi], bq1, acc[mi][1], 0, 0, 0);
            acc[mi][2] = __builtin_amdgcn_mfma_f32_16x16x32_bf16(af[mi], bq2, acc[mi][2], 0, 0, 0);
            acc[mi][3] = __builtin_amdgcn_mfma_f32_16x16x32_bf16(af[mi], bq3, acc[mi][3], 0, 0, 0);
        }
        __syncthreads();
    }

#pragma unroll
    for (int mi = 0; mi < 4; ++mi)
#pragma unroll
        for (int ni = 0; ni < 4; ++ni) {
            const int r0 = bm + wr * 64 + mi * 16 + lg * 4;
            const int c0 = bn + wc * 64 + ni * 16 + l15;
#pragma unroll
            for (int i = 0; i < 4; ++i) {
                size_t idx = (size_t)(r0 + i) * Nn + c0;
                float v = acc[mi][ni][i];
                if (ACCUM) v += OUT[idx];
                OUT[idx] = v;
            }
        }
}

// ---------------------------------------------------------------------------
// Legacy 128x128 GEMM (gate GEMM only, Nn=384)
template <int ACCUM>
__global__ __launch_bounds__(256, 2)
void gemm_bt(const bf16* __restrict__ A1, int S1, int K1,
             const bf16* __restrict__ A2, int S2,
             const bf16* __restrict__ BT, int ldb,
             float* __restrict__ OUT, int Nn, int Ktot) {
    __shared__ __align__(16) unsigned short lA[128 * 32];
    __shared__ __align__(16) unsigned short lB[128 * 32];
    const int bn = blockIdx.x * 128;
    const int bm = blockIdx.y * 128;
    const int tid = threadIdx.x;
    const int wave = tid >> 6, lane = tid & 63;
    const int wr = wave >> 1, wc = wave & 1;
    const int l15 = lane & 15, lg = lane >> 4;

    f32x4 acc[4][4] = {};

    for (int k0 = 0; k0 < Ktot; k0 += 32) {
        const bf16* Ab; int koff, stA;
        if (k0 < K1) { Ab = A1; koff = k0; stA = S1; }
        else         { Ab = A2; koff = k0 - K1; stA = S2; }
#pragma unroll
        for (int q = 0; q < 2; ++q) {
            int c = wave * 128 + q * 64 + lane;
            int row = c >> 2, k8 = c & 3;
            const bf16* ga = Ab + (size_t)(bm + row) * stA + koff + k8 * 8;
            const bf16* gb = BT + (size_t)(bn + row) * ldb + k0 + k8 * 8;
            __builtin_amdgcn_global_load_lds((const GLOBAL_AS void*)ga,
                (LDS_AS void*)&lA[(wave * 128 + q * 64) * 8], 16, 0, 0);
            __builtin_amdgcn_global_load_lds((const GLOBAL_AS void*)gb,
                (LDS_AS void*)&lB[(wave * 128 + q * 64) * 8], 16, 0, 0);
        }
        __syncthreads();
        bf16x8 af[4], bfr[4];
#pragma unroll
        for (int mi = 0; mi < 4; ++mi)
            af[mi] = *reinterpret_cast<const bf16x8*>(&lA[(wr * 64 + mi * 16 + l15) * 32 + lg * 8]);
#pragma unroll
        for (int ni = 0; ni < 4; ++ni)
            bfr[ni] = *reinterpret_cast<const bf16x8*>(&lB[(wc * 64 + ni * 16 + l15) * 32 + lg * 8]);
#pragma unroll
        for (int mi = 0; mi < 4; ++mi)
#pragma unroll
            for (int ni = 0; ni < 4; ++ni)
                acc[mi][ni] = __builtin_amdgcn_mfma_f32_16x16x32_bf16(af[mi], bfr[ni], acc[mi][ni], 0, 0, 0);
        __syncthreads();
    }

#pragma unroll
    for (int mi = 0; mi < 4; ++mi)
#pragma unroll
        for (int ni = 0; ni < 4; ++ni) {
            const int r0 = bm + wr * 64 + mi * 16 + lg * 4;
            const int c0 = bn + wc * 64 + ni * 16 + l15;
#pragma unroll
            for (int i = 0; i < 4; ++i) {
                size_t idx = (size_t)(r0 + i) * Nn + c0;
                float v = acc[mi][ni][i];
                if (ACCUM) v += OUT[idx];
                OUT[idx] = v;
            }
        }
}

// ---------------------------------------------------------------------------
// Fused bias + LayerNorm + GELU; wave per row. grid N/4, block 256.
__global__ __launch_bounds__(256)
void ln_gelu_k(const float* __restrict__ ACC, const float* __restrict__ bias,
               const float* __restrict__ g, const float* __restrict__ b,
               bf16* __restrict__ hout) {
    const int wave = threadIdx.x >> 6, lane = threadIdx.x & 63;
    const int n = blockIdx.x * 4 + wave;
    float x[12];
    float s = 0.f, ss = 0.f;
#pragma unroll
    for (int j = 0; j < 12; ++j) {
        int c = lane + j * 64;
        x[j] = ACC[(size_t)n * DIM + c] + bias[c];
        s += x[j]; ss += x[j] * x[j];
    }
#pragma unroll
    for (int m = 1; m < 64; m <<= 1) { s += __shfl_xor(s, m, 64); ss += __shfl_xor(ss, m, 64); }
    const float mean = s * (1.f / DIM);
    const float var = ss * (1.f / DIM) - mean * mean;
    const float rstd = rsqrtf(var + 1e-5f);
#pragma unroll
    for (int j = 0; j < 12; ++j) {
        int c = lane + j * 64;
        float y = (x[j] - mean) * rstd * g[c] + b[c];
        hout[(size_t)n * DIM + c] = __float2bfloat16(gelu_f(y));
    }
}

// ---------------------------------------------------------------------------
__global__ __launch_bounds__(256)
void gate_k(const float* __restrict__ G1, const float* __restrict__ bg1,
            const float* __restrict__ Wg2, const float* __restrict__ bg2,
            float* __restrict__ gate) {
    const int wave = threadIdx.x >> 6, lane = threadIdx.x & 63;
    const int n = blockIdx.x * 4 + wave;
    float acc = 0.f;
#pragma unroll
    for (int j = 0; j < 6; ++j) {
        int c = lane + j * 64;
        float xv = G1[(size_t)n * 384 + c] + bg1[c];
        acc += gelu_f(xv) * Wg2[c];
    }
#pragma unroll
    for (int m = 1; m < 64; m <<= 1) acc += __shfl_xor(acc, m, 64);
    if (lane == 0) gate[n] = acc + bg2[0];
}

// ---------------------------------------------------------------------------
__device__ __forceinline__ int lower_bound_ng(const int* ng, int key) {
    int lo = 0, hi = N_NODES;
    while (lo < hi) { int mid = (lo + hi) >> 1; if (ng[mid] < key) lo = mid + 1; else hi = mid; }
    return lo;
}

__global__ __launch_bounds__(256)
void seg_stats_k(const float* __restrict__ gate, const int* __restrict__ ng,
                 float* __restrict__ gmax, float* __restrict__ gden) {
    __shared__ float red[256];
    const int b = blockIdx.x, t = threadIdx.x;
    const int start = lower_bound_ng(ng, b), end = lower_bound_ng(ng, b + 1);
    float m = -1e30f;
    for (int n = start + t; n < end; n += 256) m = fmaxf(m, gate[n]);
    red[t] = m; __syncthreads();
    for (int s = 128; s > 0; s >>= 1) { if (t < s) red[t] = fmaxf(red[t], red[t + s]); __syncthreads(); }
    const float gm = red[0]; __syncthreads();
    float ssum = 0.f;
    for (int n = start + t; n < end; n += 256) ssum += expf(gate[n] - gm);
    red[t] = ssum; __syncthreads();
    for (int s = 128; s > 0; s >>= 1) { if (t < s) red[t] += red[t + s]; __syncthreads(); }
    if (t == 0) { gmax[b] = gm; gden[b] = fmaxf(red[0], 1e-30f); }
}

__global__ __launch_bounds__(768)
void pool_k(const bf16* __restrict__ h, const float* __restrict__ gate,
            const int* __restrict__ ng, const float* __restrict__ gmax,
            const float* __restrict__ gden, float* __restrict__ grep) {
    const int b = blockIdx.x, c = threadIdx.x;
    const int start = lower_bound_ng(ng, b), end = lower_bound_ng(ng, b + 1);
    const float gm = gmax[b], inv = 1.0f / gden[b];
    const unsigned short* hv = (const unsigned short*)h;
    float a0 = 0.f, a1 = 0.f;
    int n = start;
    for (; n + 1 < end; n += 2) {
        float w0 = expf(gate[n] - gm) * inv;
        float w1 = expf(gate[n + 1] - gm) * inv;
        a0 += w0 * bfu(hv[(size_t)n * DIM + c]);
        a1 += w1 * bfu(hv[(size_t)(n + 1) * DIM + c]);
    }
    if (n < end) a0 += expf(gate[n] - gm) * inv * bfu(hv[(size_t)n * DIM + c]);
    grep[(size_t)b * DIM + c] = a0 + a1;
}

// ---------------------------------------------------------------------------
__global__ __launch_bounds__(512)
void cls_k(const float* __restrict__ grep, const float* __restrict__ Wc1,
           const float* __restrict__ bc1, const float* __restrict__ lng,
           const float* __restrict__ lnb, const float* __restrict__ Wc2,
           const float* __restrict__ bc2, float* __restrict__ out) {
    __shared__ float gr[DIM];
    __shared__ float red[512];
    const int b = blockIdx.x, j = threadIdx.x;
    for (int c = j; c < DIM; c += 512) gr[c] = grep[(size_t)b * DIM + c];
    __syncthreads();
    float a = bc1[j];
#pragma unroll 4
    for (int k = 0; k < DIM; ++k) a = fmaf(gr[k], Wc1[(size_t)k * 512 + j], a);
    red[j] = a; __syncthreads();
    for (int s = 256; s > 0; s >>= 1) { if (j < s) red[j] += red[j + s]; __syncthreads(); }
    const float mean = red[0] * (1.f / 512.f);
    __syncthreads();
    red[j] = (a - mean) * (a - mean); __syncthreads();
    for (int s = 256; s > 0; s >>= 1) { if (j < s) red[j] += red[j + s]; __syncthreads(); }
    const float rstd = rsqrtf(red[0] * (1.f / 512.f) + 1e-5f);
    __syncthreads();
    const float z = gelu_f((a - mean) * rstd * lng[j] + lnb[j]);
    red[j] = z * Wc2[2 * j + 0]; __syncthreads();
    for (int s = 256; s > 0; s >>= 1) { if (j < s) red[j] += red[j + s]; __syncthreads(); }
    const float l0 = red[0] + bc2[0];
    __syncthreads();
    red[j] = z * Wc2[2 * j + 1]; __syncthreads();
    for (int s = 256; s > 0; s >>= 1) { if (j < s) red[j] += red[j + s]; __syncthreads(); }
    if (j == 0) {
        const float l1 = red[0] + bc2[1];
        const float mx = fmaxf(l0, l1);
        const float lse = mx + logf(expf(l0 - mx) + expf(l1 - mx));
        out[2 * b + 0] = l0 - lse;
        out[2 * b + 1] = l1 - lse;
    }
}

// ---------------------------------------------------------------------------
extern "C" void kernel_launch(void* const* d_in, const int* in_sizes, int n_in,
                              void* d_out, int out_size, void* d_ws, size_t ws_size,
                              hipStream_t stream) {
    const float* type_vec = (const float*)d_in[0];
    const float* code_vec = (const float*)d_in[1];
    const float* W_in     = (const float*)d_in[2];
    const float* b_in     = (const float*)d_in[3];
    const float* ln_in_g  = (const float*)d_in[4];
    const float* ln_in_b  = (const float*)d_in[5];
    const float* W_rel    = (const float*)d_in[6];
    const float* W_loop   = (const float*)d_in[7];
    const float* rgcn_bias= (const float*)d_in[8];
    const float* ln_g     = (const float*)d_in[9];
    const float* ln_b     = (const float*)d_in[10];
    const float* Wg1      = (const float*)d_in[11];
    const float* bg1      = (const float*)d_in[12];
    const float* Wg2      = (const float*)d_in[13];
    const float* bg2      = (const float*)d_in[14];
    const float* Wc1      = (const float*)d_in[15];
    const float* bc1      = (const float*)d_in[16];
    const float* ln_c_g   = (const float*)d_in[17];
    const float* ln_c_b   = (const float*)d_in[18];
    const float* Wc2      = (const float*)d_in[19];
    const float* bc2      = (const float*)d_in[20];
    const int* src        = (const int*)d_in[21];
    const int* dst        = (const int*)d_in[22];
    const int* etype      = (const int*)d_in[23];
    const int* node_graph = (const int*)d_in[24];

    char* ws = (char*)d_ws;

    // pick relation-chunk width nc by workspace size
    auto need = [](int nc) -> size_t {
        size_t base = 0;
        auto al = [&](size_t sz) { base = (base + sz + 255) & ~(size_t)255; };
        al((size_t)N_NODES * DIM * 2);        // H
        al((size_t)N_NODES * DIM * 4);        // ACC
        al((size_t)DIM * KIN * 2);            // WIN
        al((size_t)3 * DIM * KSTACK * 2);     // WST
        al((size_t)384 * DIM * 2);            // WG1
        size_t open = base;
        al((size_t)N_NODES * nc * DIM * 2);   // AGG
        al((size_t)(NKEY + 1) * 4);           // RP2
        al((size_t)NKEY * 4);                 // CUR2
        al((size_t)NKEY * 4);                 // DEG2
        al((size_t)N_EDGES * 4);              // EIX
        al((size_t)N_NODES * 4);              // GATE
        al(256); al(256);                     // GMAX, GDEN
        al((size_t)NGR * DIM * 4);            // GREP
        size_t xend = open + (size_t)N_NODES * KIN * 2;
        return base > xend ? base : xend;
    };
    int nc = 1;
    if (ws_size >= need(4)) nc = 4;
    else if (ws_size >= need(2)) nc = 2;

    // layout
    size_t off = 0;
    auto alloc = [&](size_t sz) { size_t r = off; off = (off + sz + 255) & ~(size_t)255; return r; };
    bf16*  h_bf  = (bf16*)(ws + alloc((size_t)N_NODES * DIM * 2));
    float* ACC   = (float*)(ws + alloc((size_t)N_NODES * DIM * 4));
    bf16*  WinT  = (bf16*)(ws + alloc((size_t)DIM * KIN * 2));
    bf16*  Wst   = (bf16*)(ws + alloc((size_t)3 * DIM * KSTACK * 2));
    bf16*  Wg1T  = (bf16*)(ws + alloc((size_t)384 * DIM * 2));
    size_t open  = off;
    bf16*  AGG   = (bf16*)(ws + alloc((size_t)N_NODES * nc * DIM * 2));
    int*   rp2   = (int*)(ws + alloc((size_t)(NKEY + 1) * 4));
    int*   cur2  = (int*)(ws + alloc((size_t)NKEY * 4));
    int*   deg2  = (int*)(ws + alloc((size_t)NKEY * 4));
    int*   eidx  = (int*)(ws + alloc((size_t)N_EDGES * 4));
    float* gate  = (float*)(ws + alloc((size_t)N_NODES * 4));
    float* gmax  = (float*)(ws + alloc(256));
    float* gden  = (float*)(ws + alloc(256));
    float* grep  = (float*)(ws + alloc((size_t)NGR * DIM * 4));
    bf16*  Xbf   = (bf16*)(ws + open);      // [N][800]; dead after input GEMM
    float* G1    = ACC;                     // reuse after layers

    // --- weight prep
    tcast_k<<<dim3(25, 24), 256, 0, stream>>>(W_in, WinT, 784, DIM, KIN, KIN);
    wprep_k<<<dim3(24, 24, 27), 256, 0, stream>>>(W_rel, W_loop, Wst);
    tcast_k<<<dim3(24, 12), 256, 0, stream>>>(Wg1, Wg1T, DIM, 384, DIM, DIM);

    // --- input projection (X overlaps AGG/CSR region; consumed before they're written)
    concat_k<<<N_NODES, 256, 0, stream>>>(type_vec, code_vec, Xbf);
    gemm_bl2<0><<<768, 512, 0, stream>>>(Xbf, KIN, KIN, Xbf, KIN, WinT, KIN, ACC, DIM, KIN, 3);
    ln_gelu_k<<<N_NODES / 4, 256, 0, stream>>>(ACC, b_in, ln_in_g, ln_in_b, h_bf);

    // --- (dst,type) CSR build (after X is dead)
    hipMemsetAsync(deg2, 0, (size_t)NKEY * 4, stream);
    hist2_k<<<N_EDGES / 256, 256, 0, stream>>>(dst, etype, deg2);
    scan2_k<<<1, 1024, 0, stream>>>(deg2, rp2, cur2);
    place2_k<<<N_EDGES / 256, 256, 0, stream>>>(src, dst, etype, cur2, eidx);

    // --- RGCN layers: per chunk of nc relations, gather then accumulate-GEMM
    const int nchunks = 8 / nc;
    for (int l = 0; l < 3; ++l) {
        bf16* Wl = Wst + (size_t)l * DIM * KSTACK;
        for (int c = 0; c < nchunks; ++c) {
            const int rbase = c * nc;
            if (nc == 1)      gather2_k<1><<<N_NODES / 4, 256, 0, stream>>>(h_bf, rp2, eidx, AGG, rbase);
            else if (nc == 2) gather2_k<2><<<N_NODES / 4, 256, 0, stream>>>(h_bf, rp2, eidx, AGG, rbase);
            else              gather2_k<4><<<N_NODES / 4, 256, 0, stream>>>(h_bf, rp2, eidx, AGG, rbase);
            if (c == 0) {
                gemm_bl2<0><<<768, 512, 0, stream>>>(
                    h_bf, DIM, DIM, AGG, nc * DIM, Wl, KSTACK, ACC, DIM, DIM + nc * DIM, 3);
            } else {
                gemm_bl2<1><<<768, 512, 0, stream>>>(
                    AGG, nc * DIM, nc * DIM, AGG, nc * DIM,
                    Wl + (size_t)DIM * (1 + rbase), KSTACK, ACC, DIM, nc * DIM, 3);
            }
        }
        ln_gelu_k<<<N_NODES / 4, 256, 0, stream>>>(ACC, rgcn_bias + l * DIM, ln_g + l * DIM,
                                                   ln_b + l * DIM, h_bf);
    }

    // --- global attention pooling
    gemm_bt<0><<<dim3(3, 256), 256, 0, stream>>>(
        h_bf, DIM, DIM, h_bf, DIM, Wg1T, DIM, G1, 384, DIM);
    gate_k<<<N_NODES / 4, 256, 0, stream>>>(G1, bg1, Wg2, bg2, gate);
    seg_stats_k<<<NGR, 256, 0, stream>>>(gate, node_graph, gmax, gden);
    pool_k<<<NGR, 768, 0, stream>>>(h_bf, gate, node_graph, gmax, gden, grep);

    // --- classifier head
    cls_k<<<NGR, 512, 0, stream>>>(grep, Wc1, bc1, ln_c_g, ln_c_b, Wc2, bc2, (float*)d_out);
}

// Round 11
// 2492.099 us; speedup vs baseline: 1.4824x; 1.4824x over previous
//
#include <hip/hip_runtime.h>
#include <hip/hip_bf16.h>

typedef __hip_bfloat16 bf16;
typedef __attribute__((ext_vector_type(8))) __bf16 bf16x8;
typedef __attribute__((ext_vector_type(4))) float f32x4;

#define N_NODES 32768
#define N_EDGES 262144
#define DIM 768
#define NGR 64
#define KIN 800     // 784 padded to 32
#define KSTACK 6912 // self(768) + 8*768
#define NKEY (N_NODES * 8)

#define GLOBAL_AS __attribute__((address_space(1)))
#define LDS_AS __attribute__((address_space(3)))

__device__ __forceinline__ float gelu_f(float x) {
    return 0.5f * x * (1.0f + erff(x * 0.70710678118654752f));
}
__device__ __forceinline__ float bfu(unsigned short v) {
    union { unsigned u; float f; } x; x.u = (unsigned)v << 16; return x.f;
}
__device__ __forceinline__ unsigned short fbf(float f) {
    bf16 t = __float2bfloat16(f); return *(unsigned short*)&t;
}

// ---------------------------------------------------------------------------
// Transpose + cast fp32 [I][O] -> bf16 [O][ostride], zero-pad i in [I,Ipad)
__global__ __launch_bounds__(256)
void tcast_k(const float* __restrict__ in, bf16* __restrict__ out, int I, int O,
             int Ipad, int ostride) {
    __shared__ float t[32][33];
    const int i0 = blockIdx.x * 32, o0 = blockIdx.y * 32;
    const int tx = threadIdx.x & 31, ty = threadIdx.x >> 5;
#pragma unroll
    for (int q = 0; q < 4; ++q) {
        int i = i0 + ty + q * 8, o = o0 + tx;
        t[ty + q * 8][tx] = (i < I) ? in[(size_t)i * O + o] : 0.0f;
    }
    __syncthreads();
#pragma unroll
    for (int q = 0; q < 4; ++q) {
        int o = o0 + ty + q * 8, i = i0 + tx;
        if (i < Ipad) out[(size_t)o * ostride + i] = __float2bfloat16(t[tx][ty + q * 8]);
    }
}

// ---------------------------------------------------------------------------
// Per-layer weights -> WstL[768 out][6912 K], K order: [self | r0..r7]. grid(24,24,9)
__global__ __launch_bounds__(256)
void wprep_l_k(const float* __restrict__ Wrel_l, const float* __restrict__ Wloop_l,
               bf16* __restrict__ WstL) {
    __shared__ float t[32][33];
    const int q = blockIdx.z;
    const float* in = (q < 8) ? Wrel_l + (size_t)q * DIM * DIM : Wloop_l;
    bf16* out = WstL + (q < 8 ? (q + 1) * DIM : 0);
    const int i0 = blockIdx.x * 32, o0 = blockIdx.y * 32;
    const int tx = threadIdx.x & 31, ty = threadIdx.x >> 5;
#pragma unroll
    for (int qq = 0; qq < 4; ++qq)
        t[ty + qq * 8][tx] = in[(size_t)(i0 + ty + qq * 8) * DIM + o0 + tx];
    __syncthreads();
#pragma unroll
    for (int qq = 0; qq < 4; ++qq)
        out[(size_t)(o0 + ty + qq * 8) * KSTACK + i0 + tx] =
            __float2bfloat16(t[tx][ty + qq * 8]);
}

// ---------------------------------------------------------------------------
__global__ __launch_bounds__(256)
void concat_k(const float* __restrict__ tv, const float* __restrict__ cv, bf16* __restrict__ X) {
    const int n = blockIdx.x;
    for (int c = threadIdx.x; c < KIN; c += 256) {
        float v = 0.0f;
        if (c < 16) v = tv[(size_t)n * 16 + c];
        else if (c < 784) v = cv[(size_t)n * DIM + (c - 16)];
        X[(size_t)n * KIN + c] = __float2bfloat16(v);
    }
}

// ---------------------------------------------------------------------------
// CSR build over key = dst*8 + type. deg aliased into cur (scan reads+rewrites).
__global__ __launch_bounds__(256)
void hist2_k(const int* __restrict__ dst, const int* __restrict__ et, int* __restrict__ cur) {
    int e = blockIdx.x * 256 + threadIdx.x;
    if (e < N_EDGES) atomicAdd(&cur[dst[e] * 8 + et[e]], 1);
}

__global__ __launch_bounds__(1024)
void scan2_k(int* __restrict__ cur, int* __restrict__ rp) {
    __shared__ int part[1024];
    const int t = threadIdx.x;
    const int base_i = t * 256;
    int s = 0;
    for (int i = 0; i < 256; ++i) s += cur[base_i + i];
    part[t] = s; __syncthreads();
    for (int st = 1; st < 1024; st <<= 1) {
        int v = (t >= st) ? part[t - st] : 0;
        __syncthreads();
        part[t] += v;
        __syncthreads();
    }
    int run = part[t] - s;
    for (int i = 0; i < 256; ++i) {
        int d = cur[base_i + i];          // read old deg, then overwrite
        rp[base_i + i] = run; cur[base_i + i] = run;
        run += d;
    }
    if (t == 1023) rp[NKEY] = run;
}

__global__ __launch_bounds__(256)
void place2_k(const int* __restrict__ src, const int* __restrict__ dst,
              const int* __restrict__ et, int* __restrict__ cur,
              unsigned short* __restrict__ eidx) {
    int e = blockIdx.x * 256 + threadIdx.x;
    if (e >= N_EDGES) return;
    int pos = atomicAdd(&cur[dst[e] * 8 + et[e]], 1);
    eidx[pos] = (unsigned short)src[e];
}

// ---------------------------------------------------------------------------
// Gather-aggregate for NC relations [rbase, rbase+NC), exact CSR ranges.
// Writes AGG rows with row-stride `ostride` at column offset `colbase`.
template <int NC>
__global__ __launch_bounds__(256)
void gather2_k(const bf16* __restrict__ h, const int* __restrict__ rp2,
               const unsigned short* __restrict__ eidx, bf16* __restrict__ AGG,
               int rbase, int ostride, int colbase) {
    const int wave = threadIdx.x >> 6, lane = threadIdx.x & 63;
    const int n = blockIdx.x * 4 + wave;
    const int c0 = 2 * lane;
    unsigned short* outrow = (unsigned short*)&AGG[(size_t)n * ostride + colbase];
    const int* bp = &rp2[n * 8 + rbase];
#pragma unroll 1
    for (int sel = 0; sel < NC; ++sel) {
        const int s = bp[sel], e = bp[sel + 1];
        float2 f[6] = {};
        for (int t = s; t < e; ++t) {
            const unsigned short* hs = (const unsigned short*)&h[(size_t)eidx[t] * DIM];
#pragma unroll
            for (int j = 0; j < 6; ++j) {
                ushort2 u = *(const ushort2*)&hs[c0 + j * 128];
                f[j].x += bfu(u.x); f[j].y += bfu(u.y);
            }
        }
#pragma unroll
        for (int j = 0; j < 6; ++j) {
            ushort2 o; o.x = fbf(f[j].x); o.y = fbf(f[j].y);
            *(ushort2*)&outrow[sel * DIM + c0 + j * 128] = o;
        }
    }
}

// ---------------------------------------------------------------------------
// gemm256: C[M,Nn](bf16) = / += A[M,K] @ BT[Nn,K]^T. BM=128, BN=256, BK=32.
// Round-7 best-measured structure: 3-deep LDS pipeline with counted vmcnt
// (stage(t+2) issued at iter t, vmcnt(6) waits only stage(t)); 0-conflict
// source-side swizzle; XCD-chunked block swizzle; (512,4) = 128-VGPR cap.
// MODE 0: store bf16. MODE 1: read-modify-write bf16.
template <int MODE>
__global__ __launch_bounds__(512, 4)
void gemm256(const bf16* __restrict__ A1, int S1, int K1,
             const bf16* __restrict__ A2, int S2,
             const bf16* __restrict__ BT, int ldb,
             bf16* __restrict__ OUT, int Nn, int Ktot, int nbx) {
    __shared__ __align__(16) unsigned short lA[3][128 * 32];
    __shared__ __align__(16) unsigned short lB[3][256 * 32];
    const int nblk = gridDim.x, qx = nblk >> 3, bid = blockIdx.x;
    const int wgid = (bid & 7) * qx + (bid >> 3);
    const int bx = wgid % nbx, by = wgid / nbx;
    const int bn = bx * 256, bm = by * 128;
    const int tid = threadIdx.x;
    const int wave = tid >> 6, lane = tid & 63;
    const int wr = wave >> 2, wc = wave & 3;
    const int l15 = lane & 15, lg = lane >> 4;
    const int swz = (lg ^ ((l15 >> 1) & 3)) * 8;

    f32x4 acc[4][4] = {};
    const int nkt = Ktot >> 5;

    auto stage = [&](int t, int buf) {
        const int k0 = t * 32;
        const bf16* Ab; int koff, stA;
        if (k0 < K1) { Ab = A1; koff = k0; stA = S1; }
        else         { Ab = A2; koff = k0 - K1; stA = S2; }
        {
            const int row = tid >> 2, k8 = tid & 3;
            const int ks = (k8 ^ ((row >> 1) & 3)) * 8;
            const bf16* ga = Ab + (size_t)(bm + row) * stA + koff + ks;
            __builtin_amdgcn_global_load_lds((const GLOBAL_AS void*)ga,
                (LDS_AS void*)&lA[buf][(wave * 64) * 8], 16, 0, 0);
        }
#pragma unroll
        for (int qq = 0; qq < 2; ++qq) {
            const int c = qq * 512 + tid;
            const int row = c >> 2, k8 = c & 3;
            const int ks = (k8 ^ ((row >> 1) & 3)) * 8;
            const bf16* gb = BT + (size_t)(bn + row) * ldb + k0 + ks;
            __builtin_amdgcn_global_load_lds((const GLOBAL_AS void*)gb,
                (LDS_AS void*)&lB[buf][((qq * 8 + wave) * 64) * 8], 16, 0, 0);
        }
    };

    stage(0, 0);
    if (nkt > 1) stage(1, 1);

    int rb = 0;
    for (int t = 0; t < nkt; ++t) {
        if (t + 2 < nkt) {
            int sb = rb + 2; if (sb >= 3) sb -= 3;
            stage(t + 2, sb);
            asm volatile("s_waitcnt vmcnt(6)" ::: "memory");
        } else if (t + 1 < nkt) {
            asm volatile("s_waitcnt vmcnt(3)" ::: "memory");
        } else {
            asm volatile("s_waitcnt vmcnt(0)" ::: "memory");
        }
        __builtin_amdgcn_s_barrier();
        __builtin_amdgcn_sched_barrier(0);

        bf16x8 af[4], bfr[4];
#pragma unroll
        for (int mi = 0; mi < 4; ++mi) {
            const int r = wr * 64 + mi * 16 + l15;
            af[mi] = *reinterpret_cast<const bf16x8*>(&lA[rb][r * 32 + swz]);
        }
#pragma unroll
        for (int ni = 0; ni < 4; ++ni) {
            const int r = wc * 64 + ni * 16 + l15;
            bfr[ni] = *reinterpret_cast<const bf16x8*>(&lB[rb][r * 32 + swz]);
        }
        __builtin_amdgcn_s_setprio(1);
#pragma unroll
        for (int mi = 0; mi < 4; ++mi)
#pragma unroll
            for (int ni = 0; ni < 4; ++ni)
                acc[mi][ni] = __builtin_amdgcn_mfma_f32_16x16x32_bf16(af[mi], bfr[ni], acc[mi][ni], 0, 0, 0);
        __builtin_amdgcn_s_setprio(0);
        __builtin_amdgcn_sched_barrier(0);
        __builtin_amdgcn_s_barrier();

        rb = (rb == 2) ? 0 : rb + 1;
    }

    unsigned short* O = (unsigned short*)OUT;
#pragma unroll
    for (int mi = 0; mi < 4; ++mi)
#pragma unroll
        for (int ni = 0; ni < 4; ++ni) {
            const int r0 = bm + wr * 64 + mi * 16 + lg * 4;
            const int c0 = bn + wc * 64 + ni * 16 + l15;
#pragma unroll
            for (int i = 0; i < 4; ++i) {
                size_t idx = (size_t)(r0 + i) * Nn + c0;
                float v = acc[mi][ni][i];
                if (MODE == 1) v += bfu(O[idx]);
                O[idx] = fbf(v);
            }
        }
}

// ---------------------------------------------------------------------------
// Legacy 128x128 GEMM (gate GEMM only, Nn=384, fp32 out)
__global__ __launch_bounds__(256, 2)
void gemm_bt(const bf16* __restrict__ A1, int S1,
             const bf16* __restrict__ BT, int ldb,
             float* __restrict__ OUT, int Nn, int Ktot) {
    __shared__ __align__(16) unsigned short lA[128 * 32];
    __shared__ __align__(16) unsigned short lB[128 * 32];
    const int bn = blockIdx.x * 128;
    const int bm = blockIdx.y * 128;
    const int tid = threadIdx.x;
    const int wave = tid >> 6, lane = tid & 63;
    const int wr = wave >> 1, wc = wave & 1;
    const int l15 = lane & 15, lg = lane >> 4;

    f32x4 acc[4][4] = {};

    for (int k0 = 0; k0 < Ktot; k0 += 32) {
#pragma unroll
        for (int q = 0; q < 2; ++q) {
            int c = wave * 128 + q * 64 + lane;
            int row = c >> 2, k8 = c & 3;
            const bf16* ga = A1 + (size_t)(bm + row) * S1 + k0 + k8 * 8;
            const bf16* gb = BT + (size_t)(bn + row) * ldb + k0 + k8 * 8;
            __builtin_amdgcn_global_load_lds((const GLOBAL_AS void*)ga,
                (LDS_AS void*)&lA[(wave * 128 + q * 64) * 8], 16, 0, 0);
            __builtin_amdgcn_global_load_lds((const GLOBAL_AS void*)gb,
                (LDS_AS void*)&lB[(wave * 128 + q * 64) * 8], 16, 0, 0);
        }
        __syncthreads();
        bf16x8 af[4], bfr[4];
#pragma unroll
        for (int mi = 0; mi < 4; ++mi)
            af[mi] = *reinterpret_cast<const bf16x8*>(&lA[(wr * 64 + mi * 16 + l15) * 32 + lg * 8]);
#pragma unroll
        for (int ni = 0; ni < 4; ++ni)
            bfr[ni] = *reinterpret_cast<const bf16x8*>(&lB[(wc * 64 + ni * 16 + l15) * 32 + lg * 8]);
#pragma unroll
        for (int mi = 0; mi < 4; ++mi)
#pragma unroll
            for (int ni = 0; ni < 4; ++ni)
                acc[mi][ni] = __builtin_amdgcn_mfma_f32_16x16x32_bf16(af[mi], bfr[ni], acc[mi][ni], 0, 0, 0);
        __syncthreads();
    }

#pragma unroll
    for (int mi = 0; mi < 4; ++mi)
#pragma unroll
        for (int ni = 0; ni < 4; ++ni) {
            const int r0 = bm + wr * 64 + mi * 16 + lg * 4;
            const int c0 = bn + wc * 64 + ni * 16 + l15;
#pragma unroll
            for (int i = 0; i < 4; ++i)
                OUT[(size_t)(r0 + i) * Nn + c0] = acc[mi][ni][i];
        }
}

// ---------------------------------------------------------------------------
// Fused bias + LayerNorm + GELU over bf16 partials; wave per row. grid N/4.
__global__ __launch_bounds__(256)
void ln_gelu_k(const bf16* __restrict__ ACCb, const float* __restrict__ bias,
               const float* __restrict__ g, const float* __restrict__ b,
               bf16* __restrict__ hout) {
    const int wave = threadIdx.x >> 6, lane = threadIdx.x & 63;
    const int n = blockIdx.x * 4 + wave;
    const unsigned short* Ab = (const unsigned short*)ACCb;
    float x[12];
    float s = 0.f, ss = 0.f;
#pragma unroll
    for (int j = 0; j < 12; ++j) {
        int c = lane + j * 64;
        x[j] = bfu(Ab[(size_t)n * DIM + c]) + bias[c];
        s += x[j]; ss += x[j] * x[j];
    }
#pragma unroll
    for (int m = 1; m < 64; m <<= 1) { s += __shfl_xor(s, m, 64); ss += __shfl_xor(ss, m, 64); }
    const float mean = s * (1.f / DIM);
    const float var = ss * (1.f / DIM) - mean * mean;
    const float rstd = rsqrtf(var + 1e-5f);
#pragma unroll
    for (int j = 0; j < 12; ++j) {
        int c = lane + j * 64;
        float y = (x[j] - mean) * rstd * g[c] + b[c];
        hout[(size_t)n * DIM + c] = __float2bfloat16(gelu_f(y));
    }
}

// ---------------------------------------------------------------------------
__global__ __launch_bounds__(256)
void gate_k(const float* __restrict__ G1, const float* __restrict__ bg1,
            const float* __restrict__ Wg2, const float* __restrict__ bg2,
            float* __restrict__ gate) {
    const int wave = threadIdx.x >> 6, lane = threadIdx.x & 63;
    const int n = blockIdx.x * 4 + wave;
    float acc = 0.f;
#pragma unroll
    for (int j = 0; j < 6; ++j) {
        int c = lane + j * 64;
        float xv = G1[(size_t)n * 384 + c] + bg1[c];
        acc += gelu_f(xv) * Wg2[c];
    }
#pragma unroll
    for (int m = 1; m < 64; m <<= 1) acc += __shfl_xor(acc, m, 64);
    if (lane == 0) gate[n] = acc + bg2[0];
}

// ---------------------------------------------------------------------------
__device__ __forceinline__ int lower_bound_ng(const int* ng, int key) {
    int lo = 0, hi = N_NODES;
    while (lo < hi) { int mid = (lo + hi) >> 1; if (ng[mid] < key) lo = mid + 1; else hi = mid; }
    return lo;
}

__global__ __launch_bounds__(256)
void seg_stats_k(const float* __restrict__ gate, const int* __restrict__ ng,
                 float* __restrict__ gmax, float* __restrict__ gden) {
    __shared__ float red[256];
    const int b = blockIdx.x, t = threadIdx.x;
    const int start = lower_bound_ng(ng, b), end = lower_bound_ng(ng, b + 1);
    float m = -1e30f;
    for (int n = start + t; n < end; n += 256) m = fmaxf(m, gate[n]);
    red[t] = m; __syncthreads();
    for (int s = 128; s > 0; s >>= 1) { if (t < s) red[t] = fmaxf(red[t], red[t + s]); __syncthreads(); }
    const float gm = red[0]; __syncthreads();
    float ssum = 0.f;
    for (int n = start + t; n < end; n += 256) ssum += expf(gate[n] - gm);
    red[t] = ssum; __syncthreads();
    for (int s = 128; s > 0; s >>= 1) { if (t < s) red[t] += red[t + s]; __syncthreads(); }
    if (t == 0) { gmax[b] = gm; gden[b] = fmaxf(red[0], 1e-30f); }
}

__global__ __launch_bounds__(768)
void pool_k(const bf16* __restrict__ h, const float* __restrict__ gate,
            const int* __restrict__ ng, const float* __restrict__ gmax,
            const float* __restrict__ gden, float* __restrict__ grep) {
    const int b = blockIdx.x, c = threadIdx.x;
    const int start = lower_bound_ng(ng, b), end = lower_bound_ng(ng, b + 1);
    const float gm = gmax[b], inv = 1.0f / gden[b];
    const unsigned short* hv = (const unsigned short*)h;
    float a0 = 0.f, a1 = 0.f;
    int n = start;
    for (; n + 1 < end; n += 2) {
        float w0 = expf(gate[n] - gm) * inv;
        float w1 = expf(gate[n + 1] - gm) * inv;
        a0 += w0 * bfu(hv[(size_t)n * DIM + c]);
        a1 += w1 * bfu(hv[(size_t)(n + 1) * DIM + c]);
    }
    if (n < end) a0 += expf(gate[n] - gm) * inv * bfu(hv[(size_t)n * DIM + c]);
    grep[(size_t)b * DIM + c] = a0 + a1;
}

// ---------------------------------------------------------------------------
__global__ __launch_bounds__(512)
void cls_k(const float* __restrict__ grep, const float* __restrict__ Wc1,
           const float* __restrict__ bc1, const float* __restrict__ lng,
           const float* __restrict__ lnb, const float* __restrict__ Wc2,
           const float* __restrict__ bc2, float* __restrict__ out) {
    __shared__ float gr[DIM];
    __shared__ float red[512];
    const int b = blockIdx.x, j = threadIdx.x;
    for (int c = j; c < DIM; c += 512) gr[c] = grep[(size_t)b * DIM + c];
    __syncthreads();
    float a = bc1[j];
#pragma unroll 4
    for (int k = 0; k < DIM; ++k) a = fmaf(gr[k], Wc1[(size_t)k * 512 + j], a);
    red[j] = a; __syncthreads();
    for (int s = 256; s > 0; s >>= 1) { if (j < s) red[j] += red[j + s]; __syncthreads(); }
    const float mean = red[0] * (1.f / 512.f);
    __syncthreads();
    red[j] = (a - mean) * (a - mean); __syncthreads();
    for (int s = 256; s > 0; s >>= 1) { if (j < s) red[j] += red[j + s]; __syncthreads(); }
    const float rstd = rsqrtf(red[0] * (1.f / 512.f) + 1e-5f);
    __syncthreads();
    const float z = gelu_f((a - mean) * rstd * lng[j] + lnb[j]);
    red[j] = z * Wc2[2 * j + 0]; __syncthreads();
    for (int s = 256; s > 0; s >>= 1) { if (j < s) red[j] += red[j + s]; __syncthreads(); }
    const float l0 = red[0] + bc2[0];
    __syncthreads();
    red[j] = z * Wc2[2 * j + 1]; __syncthreads();
    for (int s = 256; s > 0; s >>= 1) { if (j < s) red[j] += red[j + s]; __syncthreads(); }
    if (j == 0) {
        const float l1 = red[0] + bc2[1];
        const float mx = fmaxf(l0, l1);
        const float lse = mx + logf(expf(l0 - mx) + expf(l1 - mx));
        out[2 * b + 0] = l0 - lse;
        out[2 * b + 1] = l1 - lse;
    }
}

// ---------------------------------------------------------------------------
extern "C" void kernel_launch(void* const* d_in, const int* in_sizes, int n_in,
                              void* d_out, int out_size, void* d_ws, size_t ws_size,
                              hipStream_t stream) {
    const float* type_vec = (const float*)d_in[0];
    const float* code_vec = (const float*)d_in[1];
    const float* W_in     = (const float*)d_in[2];
    const float* b_in     = (const float*)d_in[3];
    const float* ln_in_g  = (const float*)d_in[4];
    const float* ln_in_b  = (const float*)d_in[5];
    const float* W_rel    = (const float*)d_in[6];
    const float* W_loop   = (const float*)d_in[7];
    const float* rgcn_bias= (const float*)d_in[8];
    const float* ln_g     = (const float*)d_in[9];
    const float* ln_b     = (const float*)d_in[10];
    const float* Wg1      = (const float*)d_in[11];
    const float* bg1      = (const float*)d_in[12];
    const float* Wg2      = (const float*)d_in[13];
    const float* bg2      = (const float*)d_in[14];
    const float* Wc1      = (const float*)d_in[15];
    const float* bc1      = (const float*)d_in[16];
    const float* ln_c_g   = (const float*)d_in[17];
    const float* ln_c_b   = (const float*)d_in[18];
    const float* Wc2      = (const float*)d_in[19];
    const float* bc2      = (const float*)d_in[20];
    const int* src        = (const int*)d_in[21];
    const int* dst        = (const int*)d_in[22];
    const int* etype      = (const int*)d_in[23];
    const int* node_graph = (const int*)d_in[24];

    char* ws = (char*)d_ws;

    // layout: fixed prefix, AGG (sized by nc) last. X/WIN/G1 overlay AGG region.
    auto lay = [&](int nc, bool doAssign,
                   bf16*& h_bf, bf16*& ACCb, bf16*& WstL, int*& rp2, int*& cur2,
                   unsigned short*& eidx, float*& gate, float*& gmax, float*& gden,
                   float*& grep, bf16*& AGG) -> size_t {
        size_t off = 0;
        auto alloc = [&](size_t sz) { size_t r = off; off = (off + sz + 255) & ~(size_t)255; return r; };
        size_t oH   = alloc((size_t)N_NODES * DIM * 2);
        size_t oAC  = alloc((size_t)N_NODES * DIM * 2);
        size_t oWL  = alloc((size_t)DIM * KSTACK * 2);
        size_t oRP  = alloc((size_t)(NKEY + 1) * 4);
        size_t oCU  = alloc((size_t)NKEY * 4);
        size_t oEI  = alloc((size_t)N_EDGES * 2);
        size_t oGA  = alloc((size_t)N_NODES * 4);
        size_t oGM  = alloc(256);
        size_t oGD  = alloc(256);
        size_t oGR  = alloc((size_t)NGR * DIM * 4);
        size_t oAG  = alloc((size_t)N_NODES * nc * DIM * 2);
        if (doAssign) {
            h_bf = (bf16*)(ws + oH);   ACCb = (bf16*)(ws + oAC);
            WstL = (bf16*)(ws + oWL);  rp2  = (int*)(ws + oRP);
            cur2 = (int*)(ws + oCU);   eidx = (unsigned short*)(ws + oEI);
            gate = (float*)(ws + oGA); gmax = (float*)(ws + oGM);
            gden = (float*)(ws + oGD); grep = (float*)(ws + oGR);
            AGG  = (bf16*)(ws + oAG);
        }
        return off;
    };

    bf16 *h_bf, *ACCb, *WstL, *AGG; int *rp2, *cur2; unsigned short* eidx;
    float *gate, *gmax, *gden, *grep;
    bf16 *d0=nullptr,*d1=nullptr,*d2=nullptr,*d3=nullptr; int *d4=nullptr,*d5=nullptr;
    unsigned short* d6=nullptr; float *d7=nullptr,*d8=nullptr,*d9=nullptr,*d10=nullptr;
    const bool big = ws_size >= lay(8, false, d0,d1,d2,d4,d5,d6,d7,d8,d9,d10,d3);
    const int nc = big ? 8 : 4;
    lay(nc, true, h_bf, ACCb, WstL, rp2, cur2, eidx, gate, gmax, gden, grep, AGG);

    // AGG-region overlays
    bf16* Xbf  = AGG;                                          // [N][800] input concat
    bf16* WinT = (bf16*)((char*)AGG + (size_t)N_NODES * KIN * 2); // [768][800]
    float* G1  = (float*)AGG;                                  // [N][384] at gate time

    const int AGW = nc * DIM;  // AGG row stride (elements)

    // --- input projection (X/WIN live in AGG region; dead before gathers)
    tcast_k<<<dim3(25, 24), 256, 0, stream>>>(W_in, WinT, 784, DIM, KIN, KIN);
    concat_k<<<N_NODES, 256, 0, stream>>>(type_vec, code_vec, Xbf);
    gemm256<0><<<768, 512, 0, stream>>>(Xbf, KIN, KIN, Xbf, KIN, WinT, KIN, ACCb, DIM, KIN, 3);
    ln_gelu_k<<<N_NODES / 4, 256, 0, stream>>>(ACCb, b_in, ln_in_g, ln_in_b, h_bf);

    // --- (dst,type) CSR build
    hipMemsetAsync(cur2, 0, (size_t)NKEY * 4, stream);
    hist2_k<<<N_EDGES / 256, 256, 0, stream>>>(dst, etype, cur2);
    scan2_k<<<1, 1024, 0, stream>>>(cur2, rp2);
    place2_k<<<N_EDGES / 256, 256, 0, stream>>>(src, dst, etype, cur2, eidx);

    // --- RGCN layers
    for (int l = 0; l < 3; ++l) {
        wprep_l_k<<<dim3(24, 24, 9), 256, 0, stream>>>(
            W_rel + (size_t)l * 8 * DIM * DIM, W_loop + (size_t)l * DIM * DIM, WstL);
        if (nc == 8) {
            gather2_k<4><<<N_NODES / 4, 256, 0, stream>>>(h_bf, rp2, eidx, AGG, 0, AGW, 0);
            gather2_k<4><<<N_NODES / 4, 256, 0, stream>>>(h_bf, rp2, eidx, AGG, 4, AGW, 4 * DIM);
            gemm256<0><<<768, 512, 0, stream>>>(
                h_bf, DIM, DIM, AGG, AGW, WstL, KSTACK, ACCb, DIM, KSTACK, 3);
        } else {
            gather2_k<4><<<N_NODES / 4, 256, 0, stream>>>(h_bf, rp2, eidx, AGG, 0, AGW, 0);
            gemm256<0><<<768, 512, 0, stream>>>(
                h_bf, DIM, DIM, AGG, AGW, WstL, KSTACK, ACCb, DIM, DIM + 4 * DIM, 3);
            gather2_k<4><<<N_NODES / 4, 256, 0, stream>>>(h_bf, rp2, eidx, AGG, 4, AGW, 0);
            gemm256<1><<<768, 512, 0, stream>>>(
                AGG, AGW, AGW, AGG, AGW, WstL + (size_t)DIM * 5, KSTACK, ACCb, DIM, 4 * DIM, 3);
        }
        ln_gelu_k<<<N_NODES / 4, 256, 0, stream>>>(ACCb, rgcn_bias + l * DIM, ln_g + l * DIM,
                                                   ln_b + l * DIM, h_bf);
    }

    // --- global attention pooling (G1/Wg1T overlay AGG region, AGG dead)
    bf16* Wg1T = (bf16*)((char*)AGG + 60 * 1024 * 1024);
    tcast_k<<<dim3(24, 12), 256, 0, stream>>>(Wg1, Wg1T, DIM, 384, DIM, DIM);
    gemm_bt<<<dim3(3, 256), 256, 0, stream>>>(h_bf, DIM, Wg1T, DIM, G1, 384, DIM);
    gate_k<<<N_NODES / 4, 256, 0, stream>>>(G1, bg1, Wg2, bg2, gate);
    seg_stats_k<<<NGR, 256, 0, stream>>>(gate, node_graph, gmax, gden);
    pool_k<<<NGR, 768, 0, stream>>>(h_bf, gate, node_graph, gmax, gden, grep);

    // --- classifier head
    cls_k<<<NGR, 512, 0, stream>>>(grep, Wc1, bc1, ln_c_g, ln_c_b, Wc2, bc2, (float*)d_out);
}

// Round 12
// 2449.423 us; speedup vs baseline: 1.5082x; 1.0174x over previous
//
#include <hip/hip_runtime.h>
#include <hip/hip_bf16.h>

typedef __hip_bfloat16 bf16;
typedef __attribute__((ext_vector_type(8))) __bf16 bf16x8;
typedef __attribute__((ext_vector_type(4))) float f32x4;

#define N_NODES 32768
#define N_EDGES 262144
#define DIM 768
#define NGR 64
#define KIN 800     // 784 padded to 32
#define KSTACK 6912 // self(768) + 8*768
#define NKEY (N_NODES * 8)

#define GLOBAL_AS __attribute__((address_space(1)))
#define LDS_AS __attribute__((address_space(3)))

__device__ __forceinline__ float gelu_f(float x) {
    return 0.5f * x * (1.0f + erff(x * 0.70710678118654752f));
}
__device__ __forceinline__ float bfu(unsigned short v) {
    union { unsigned u; float f; } x; x.u = (unsigned)v << 16; return x.f;
}
__device__ __forceinline__ unsigned short fbf(float f) {
    bf16 t = __float2bfloat16(f); return *(unsigned short*)&t;
}

// ---------------------------------------------------------------------------
// Transpose + cast fp32 [I][O] -> bf16 [O][ostride], zero-pad i in [I,Ipad)
__global__ __launch_bounds__(256)
void tcast_k(const float* __restrict__ in, bf16* __restrict__ out, int I, int O,
             int Ipad, int ostride) {
    __shared__ float t[32][33];
    const int i0 = blockIdx.x * 32, o0 = blockIdx.y * 32;
    const int tx = threadIdx.x & 31, ty = threadIdx.x >> 5;
#pragma unroll
    for (int q = 0; q < 4; ++q) {
        int i = i0 + ty + q * 8, o = o0 + tx;
        t[ty + q * 8][tx] = (i < I) ? in[(size_t)i * O + o] : 0.0f;
    }
    __syncthreads();
#pragma unroll
    for (int q = 0; q < 4; ++q) {
        int o = o0 + ty + q * 8, i = i0 + tx;
        if (i < Ipad) out[(size_t)o * ostride + i] = __float2bfloat16(t[tx][ty + q * 8]);
    }
}

// ---------------------------------------------------------------------------
// Per-layer weights -> WstL[768 out][6912 K], K order: [self | r0..r7]. grid(24,24,9)
__global__ __launch_bounds__(256)
void wprep_l_k(const float* __restrict__ Wrel_l, const float* __restrict__ Wloop_l,
               bf16* __restrict__ WstL) {
    __shared__ float t[32][33];
    const int q = blockIdx.z;
    const float* in = (q < 8) ? Wrel_l + (size_t)q * DIM * DIM : Wloop_l;
    bf16* out = WstL + (q < 8 ? (q + 1) * DIM : 0);
    const int i0 = blockIdx.x * 32, o0 = blockIdx.y * 32;
    const int tx = threadIdx.x & 31, ty = threadIdx.x >> 5;
#pragma unroll
    for (int qq = 0; qq < 4; ++qq)
        t[ty + qq * 8][tx] = in[(size_t)(i0 + ty + qq * 8) * DIM + o0 + tx];
    __syncthreads();
#pragma unroll
    for (int qq = 0; qq < 4; ++qq)
        out[(size_t)(o0 + ty + qq * 8) * KSTACK + i0 + tx] =
            __float2bfloat16(t[tx][ty + qq * 8]);
}

// ---------------------------------------------------------------------------
__global__ __launch_bounds__(256)
void concat_k(const float* __restrict__ tv, const float* __restrict__ cv, bf16* __restrict__ X) {
    const int n = blockIdx.x;
    for (int c = threadIdx.x; c < KIN; c += 256) {
        float v = 0.0f;
        if (c < 16) v = tv[(size_t)n * 16 + c];
        else if (c < 784) v = cv[(size_t)n * DIM + (c - 16)];
        X[(size_t)n * KIN + c] = __float2bfloat16(v);
    }
}

// ---------------------------------------------------------------------------
// CSR build over key = dst*8 + type. deg aliased into cur.
__global__ __launch_bounds__(256)
void hist2_k(const int* __restrict__ dst, const int* __restrict__ et, int* __restrict__ cur) {
    int e = blockIdx.x * 256 + threadIdx.x;
    if (e < N_EDGES) atomicAdd(&cur[dst[e] * 8 + et[e]], 1);
}

__global__ __launch_bounds__(1024)
void scan2_k(int* __restrict__ cur, int* __restrict__ rp) {
    __shared__ int part[1024];
    const int t = threadIdx.x;
    const int base_i = t * 256;
    int s = 0;
    for (int i = 0; i < 256; ++i) s += cur[base_i + i];
    part[t] = s; __syncthreads();
    for (int st = 1; st < 1024; st <<= 1) {
        int v = (t >= st) ? part[t - st] : 0;
        __syncthreads();
        part[t] += v;
        __syncthreads();
    }
    int run = part[t] - s;
    for (int i = 0; i < 256; ++i) {
        int d = cur[base_i + i];
        rp[base_i + i] = run; cur[base_i + i] = run;
        run += d;
    }
    if (t == 1023) rp[NKEY] = run;
}

__global__ __launch_bounds__(256)
void place2_k(const int* __restrict__ src, const int* __restrict__ dst,
              const int* __restrict__ et, int* __restrict__ cur,
              int* __restrict__ eidx) {
    int e = blockIdx.x * 256 + threadIdx.x;
    if (e >= N_EDGES) return;
    int pos = atomicAdd(&cur[dst[e] * 8 + et[e]], 1);
    eidx[pos] = (et[e] << 16) | src[e];
}

// ---------------------------------------------------------------------------
// Gather-aggregate for NC relations [rbase, rbase+NC), exact CSR ranges.
// ushort4-vectorized (3 x 8B per lane per row). No atomics.
template <int NC>
__global__ __launch_bounds__(256)
void gather8(const bf16* __restrict__ h, const int* __restrict__ rp2,
             const int* __restrict__ eidx, bf16* __restrict__ AGG,
             int rbase, int ostride, int colbase) {
    const int wave = threadIdx.x >> 6, lane = threadIdx.x & 63;
    const int n = blockIdx.x * 4 + wave;
    const int c0 = 4 * lane;
    unsigned short* outrow = (unsigned short*)&AGG[(size_t)n * ostride + colbase];
    const int* bp = &rp2[n * 8 + rbase];
    for (int sel = 0; sel < NC; ++sel) {
        const int s = bp[sel], e = bp[sel + 1];
        float f[12];
#pragma unroll
        for (int j = 0; j < 12; ++j) f[j] = 0.f;
        for (int t = s; t < e; ++t) {
            const int srcn = eidx[t] & 0xffff;
            const unsigned short* hs = (const unsigned short*)&h[(size_t)srcn * DIM];
#pragma unroll
            for (int j = 0; j < 3; ++j) {
                ushort4 u = *(const ushort4*)&hs[c0 + j * 256];
                f[4 * j + 0] += bfu(u.x); f[4 * j + 1] += bfu(u.y);
                f[4 * j + 2] += bfu(u.z); f[4 * j + 3] += bfu(u.w);
            }
        }
#pragma unroll
        for (int j = 0; j < 3; ++j) {
            ushort4 o;
            o.x = fbf(f[4 * j + 0]); o.y = fbf(f[4 * j + 1]);
            o.z = fbf(f[4 * j + 2]); o.w = fbf(f[4 * j + 3]);
            *(ushort4*)&outrow[sel * DIM + c0 + j * 256] = o;
        }
    }
}

// ---------------------------------------------------------------------------
// gemm384: C[M,Nn](bf16) =/+= A[M,K] @ BT[Nn,K]^T. BM=256, BN=384, BK=32.
// Tile chosen to MINIMIZE staged-byte volume (the measured round-3..11 bound):
// A x (Nn/384) + B x (M/256) = 2.26 GB vs 4.07 GB at 128x256 (-45%).
// 8 waves as 4 row-quarters x 2 col-halves; per-wave acc[4][12] (192 VGPR).
// 3-deep LDS pipeline (40KB/buf, 120KB), counted vmcnt(10/5/0); 0-conflict
// source-side swizzle; XCD-chunked block swizzle; (512,2) = 256-VGPR cap.
// MODE 0: store bf16. MODE 1: RMW bf16.
template <int MODE>
__global__ __launch_bounds__(512, 2)
void gemm384(const bf16* __restrict__ A1, int S1, int K1,
             const bf16* __restrict__ A2, int S2,
             const bf16* __restrict__ BT, int ldb,
             bf16* __restrict__ OUT, int Nn, int Ktot, int nbx) {
    __shared__ __align__(16) unsigned short lA[3][256 * 32];
    __shared__ __align__(16) unsigned short lB[3][384 * 32];
    const int nblk = gridDim.x, qx = nblk >> 3, bid = blockIdx.x;
    const int wgid = (bid & 7) * qx + (bid >> 3);
    const int bx = wgid % nbx, by = wgid / nbx;
    const int bn = bx * 384, bm = by * 256;
    const int tid = threadIdx.x;
    const int wave = tid >> 6, lane = tid & 63;
    const int wr = wave >> 1, wc = wave & 1;
    const int l15 = lane & 15, lg = lane >> 4;
    const int swz = (lg ^ ((l15 >> 1) & 3)) * 8;

    f32x4 acc[4][12] = {};
    const int nkt = Ktot >> 5;

    // stage K-tile t into buffer buf: 2 A-loads + 3 B-loads per thread
    auto stage = [&](int t, int buf) {
        const int k0 = t * 32;
        const bf16* Ab; int koff, stA;
        if (k0 < K1) { Ab = A1; koff = k0; stA = S1; }
        else         { Ab = A2; koff = k0 - K1; stA = S2; }
#pragma unroll
        for (int u = 0; u < 2; ++u) {            // A: 256x32 = 1024 chunks
            const int c = u * 512 + tid;
            const int r = c >> 2, s = c & 3;
            const int sc = (s ^ ((r >> 1) & 3)) * 8;
            const bf16* ga = Ab + (size_t)(bm + r) * stA + koff + sc;
            __builtin_amdgcn_global_load_lds((const GLOBAL_AS void*)ga,
                (LDS_AS void*)&lA[buf][(u * 512 + wave * 64) * 8], 16, 0, 0);
        }
#pragma unroll
        for (int u = 0; u < 3; ++u) {            // B: 384x32 = 1536 chunks
            const int c = u * 512 + tid;
            const int r = c >> 2, s = c & 3;
            const int sc = (s ^ ((r >> 1) & 3)) * 8;
            const bf16* gb = BT + (size_t)(bn + r) * ldb + k0 + sc;
            __builtin_amdgcn_global_load_lds((const GLOBAL_AS void*)gb,
                (LDS_AS void*)&lB[buf][(u * 512 + wave * 64) * 8], 16, 0, 0);
        }
    };

    stage(0, 0);
    if (nkt > 1) stage(1, 1);

    int rb = 0;
    for (int t = 0; t < nkt; ++t) {
        if (t + 2 < nkt) {
            int sb = rb + 2; if (sb >= 3) sb -= 3;
            stage(t + 2, sb);
            asm volatile("s_waitcnt vmcnt(10)" ::: "memory");
        } else if (t + 1 < nkt) {
            asm volatile("s_waitcnt vmcnt(5)" ::: "memory");
        } else {
            asm volatile("s_waitcnt vmcnt(0)" ::: "memory");
        }
        __builtin_amdgcn_s_barrier();
        __builtin_amdgcn_sched_barrier(0);

        bf16x8 af[4];
#pragma unroll
        for (int mi = 0; mi < 4; ++mi) {
            const int r = wr * 64 + mi * 16 + l15;
            af[mi] = *reinterpret_cast<const bf16x8*>(&lA[rb][r * 32 + swz]);
        }
        __builtin_amdgcn_s_setprio(1);
#pragma unroll
        for (int ni = 0; ni < 12; ++ni) {
            const int r = wc * 192 + ni * 16 + l15;
            bf16x8 bq = *reinterpret_cast<const bf16x8*>(&lB[rb][r * 32 + swz]);
#pragma unroll
            for (int mi = 0; mi < 4; ++mi)
                acc[mi][ni] = __builtin_amdgcn_mfma_f32_16x16x32_bf16(af[mi], bq, acc[mi][ni], 0, 0, 0);
        }
        __builtin_amdgcn_s_setprio(0);
        __builtin_amdgcn_sched_barrier(0);
        __builtin_amdgcn_s_barrier();

        rb = (rb == 2) ? 0 : rb + 1;
    }

    unsigned short* O = (unsigned short*)OUT;
#pragma unroll
    for (int mi = 0; mi < 4; ++mi)
#pragma unroll
        for (int ni = 0; ni < 12; ++ni) {
            const int r0 = bm + wr * 64 + mi * 16 + lg * 4;
            const int c0 = bn + wc * 192 + ni * 16 + l15;
#pragma unroll
            for (int i = 0; i < 4; ++i) {
                size_t idx = (size_t)(r0 + i) * Nn + c0;
                float v = acc[mi][ni][i];
                if (MODE == 1) v += bfu(O[idx]);
                O[idx] = fbf(v);
            }
        }
}

// ---------------------------------------------------------------------------
// Fused bias + LayerNorm + GELU over bf16 partials; wave per row. grid N/4.
__global__ __launch_bounds__(256)
void ln_gelu_k(const bf16* __restrict__ ACCb, const float* __restrict__ bias,
               const float* __restrict__ g, const float* __restrict__ b,
               bf16* __restrict__ hout) {
    const int wave = threadIdx.x >> 6, lane = threadIdx.x & 63;
    const int n = blockIdx.x * 4 + wave;
    const unsigned short* Ab = (const unsigned short*)ACCb;
    float x[12];
    float s = 0.f, ss = 0.f;
#pragma unroll
    for (int j = 0; j < 12; ++j) {
        int c = lane + j * 64;
        x[j] = bfu(Ab[(size_t)n * DIM + c]) + bias[c];
        s += x[j]; ss += x[j] * x[j];
    }
#pragma unroll
    for (int m = 1; m < 64; m <<= 1) { s += __shfl_xor(s, m, 64); ss += __shfl_xor(ss, m, 64); }
    const float mean = s * (1.f / DIM);
    const float var = ss * (1.f / DIM) - mean * mean;
    const float rstd = rsqrtf(var + 1e-5f);
#pragma unroll
    for (int j = 0; j < 12; ++j) {
        int c = lane + j * 64;
        float y = (x[j] - mean) * rstd * g[c] + b[c];
        hout[(size_t)n * DIM + c] = __float2bfloat16(gelu_f(y));
    }
}

// ---------------------------------------------------------------------------
// gate from bf16 G1: gate[n] = gelu(G1[n,:]+bg1) . Wg2 + bg2
__global__ __launch_bounds__(256)
void gate_k(const bf16* __restrict__ G1, const float* __restrict__ bg1,
            const float* __restrict__ Wg2, const float* __restrict__ bg2,
            float* __restrict__ gate) {
    const int wave = threadIdx.x >> 6, lane = threadIdx.x & 63;
    const int n = blockIdx.x * 4 + wave;
    const unsigned short* G = (const unsigned short*)G1;
    float acc = 0.f;
#pragma unroll
    for (int j = 0; j < 6; ++j) {
        int c = lane + j * 64;
        float xv = bfu(G[(size_t)n * 384 + c]) + bg1[c];
        acc += gelu_f(xv) * Wg2[c];
    }
#pragma unroll
    for (int m = 1; m < 64; m <<= 1) acc += __shfl_xor(acc, m, 64);
    if (lane == 0) gate[n] = acc + bg2[0];
}

// ---------------------------------------------------------------------------
__device__ __forceinline__ int lower_bound_ng(const int* ng, int key) {
    int lo = 0, hi = N_NODES;
    while (lo < hi) { int mid = (lo + hi) >> 1; if (ng[mid] < key) lo = mid + 1; else hi = mid; }
    return lo;
}

__global__ __launch_bounds__(256)
void seg_stats_k(const float* __restrict__ gate, const int* __restrict__ ng,
                 float* __restrict__ gmax, float* __restrict__ gden) {
    __shared__ float red[256];
    const int b = blockIdx.x, t = threadIdx.x;
    const int start = lower_bound_ng(ng, b), end = lower_bound_ng(ng, b + 1);
    float m = -1e30f;
    for (int n = start + t; n < end; n += 256) m = fmaxf(m, gate[n]);
    red[t] = m; __syncthreads();
    for (int s = 128; s > 0; s >>= 1) { if (t < s) red[t] = fmaxf(red[t], red[t + s]); __syncthreads(); }
    const float gm = red[0]; __syncthreads();
    float ssum = 0.f;
    for (int n = start + t; n < end; n += 256) ssum += expf(gate[n] - gm);
    red[t] = ssum; __syncthreads();
    for (int s = 128; s > 0; s >>= 1) { if (t < s) red[t] += red[t + s]; __syncthreads(); }
    if (t == 0) { gmax[b] = gm; gden[b] = fmaxf(red[0], 1e-30f); }
}

__global__ __launch_bounds__(768)
void pool_k(const bf16* __restrict__ h, const float* __restrict__ gate,
            const int* __restrict__ ng, const float* __restrict__ gmax,
            const float* __restrict__ gden, float* __restrict__ grep) {
    const int b = blockIdx.x, c = threadIdx.x;
    const int start = lower_bound_ng(ng, b), end = lower_bound_ng(ng, b + 1);
    const float gm = gmax[b], inv = 1.0f / gden[b];
    const unsigned short* hv = (const unsigned short*)h;
    float a0 = 0.f, a1 = 0.f;
    int n = start;
    for (; n + 1 < end; n += 2) {
        float w0 = expf(gate[n] - gm) * inv;
        float w1 = expf(gate[n + 1] - gm) * inv;
        a0 += w0 * bfu(hv[(size_t)n * DIM + c]);
        a1 += w1 * bfu(hv[(size_t)(n + 1) * DIM + c]);
    }
    if (n < end) a0 += expf(gate[n] - gm) * inv * bfu(hv[(size_t)n * DIM + c]);
    grep[(size_t)b * DIM + c] = a0 + a1;
}

// ---------------------------------------------------------------------------
__global__ __launch_bounds__(512)
void cls_k(const float* __restrict__ grep, const float* __restrict__ Wc1,
           const float* __restrict__ bc1, const float* __restrict__ lng,
           const float* __restrict__ lnb, const float* __restrict__ Wc2,
           const float* __restrict__ bc2, float* __restrict__ out) {
    __shared__ float gr[DIM];
    __shared__ float red[512];
    const int b = blockIdx.x, j = threadIdx.x;
    for (int c = j; c < DIM; c += 512) gr[c] = grep[(size_t)b * DIM + c];
    __syncthreads();
    float a = bc1[j];
#pragma unroll 4
    for (int k = 0; k < DIM; ++k) a = fmaf(gr[k], Wc1[(size_t)k * 512 + j], a);
    red[j] = a; __syncthreads();
    for (int s = 256; s > 0; s >>= 1) { if (j < s) red[j] += red[j + s]; __syncthreads(); }
    const float mean = red[0] * (1.f / 512.f);
    __syncthreads();
    red[j] = (a - mean) * (a - mean); __syncthreads();
    for (int s = 256; s > 0; s >>= 1) { if (j < s) red[j] += red[j + s]; __syncthreads(); }
    const float rstd = rsqrtf(red[0] * (1.f / 512.f) + 1e-5f);
    __syncthreads();
    const float z = gelu_f((a - mean) * rstd * lng[j] + lnb[j]);
    red[j] = z * Wc2[2 * j + 0]; __syncthreads();
    for (int s = 256; s > 0; s >>= 1) { if (j < s) red[j] += red[j + s]; __syncthreads(); }
    const float l0 = red[0] + bc2[0];
    __syncthreads();
    red[j] = z * Wc2[2 * j + 1]; __syncthreads();
    for (int s = 256; s > 0; s >>= 1) { if (j < s) red[j] += red[j + s]; __syncthreads(); }
    if (j == 0) {
        const float l1 = red[0] + bc2[1];
        const float mx = fmaxf(l0, l1);
        const float lse = mx + logf(expf(l0 - mx) + expf(l1 - mx));
        out[2 * b + 0] = l0 - lse;
        out[2 * b + 1] = l1 - lse;
    }
}

// ---------------------------------------------------------------------------
extern "C" void kernel_launch(void* const* d_in, const int* in_sizes, int n_in,
                              void* d_out, int out_size, void* d_ws, size_t ws_size,
                              hipStream_t stream) {
    const float* type_vec = (const float*)d_in[0];
    const float* code_vec = (const float*)d_in[1];
    const float* W_in     = (const float*)d_in[2];
    const float* b_in     = (const float*)d_in[3];
    const float* ln_in_g  = (const float*)d_in[4];
    const float* ln_in_b  = (const float*)d_in[5];
    const float* W_rel    = (const float*)d_in[6];
    const float* W_loop   = (const float*)d_in[7];
    const float* rgcn_bias= (const float*)d_in[8];
    const float* ln_g     = (const float*)d_in[9];
    const float* ln_b     = (const float*)d_in[10];
    const float* Wg1      = (const float*)d_in[11];
    const float* bg1      = (const float*)d_in[12];
    const float* Wg2      = (const float*)d_in[13];
    const float* bg2      = (const float*)d_in[14];
    const float* Wc1      = (const float*)d_in[15];
    const float* bc1      = (const float*)d_in[16];
    const float* ln_c_g   = (const float*)d_in[17];
    const float* ln_c_b   = (const float*)d_in[18];
    const float* Wc2      = (const float*)d_in[19];
    const float* bc2      = (const float*)d_in[20];
    const int* src        = (const int*)d_in[21];
    const int* dst        = (const int*)d_in[22];
    const int* etype      = (const int*)d_in[23];
    const int* node_graph = (const int*)d_in[24];

    char* ws = (char*)d_ws;

    auto lay = [&](int nc, bool doAssign,
                   bf16*& h_bf, bf16*& ACCb, bf16*& WstL, int*& rp2, int*& cur2,
                   int*& eidx, float*& gate, float*& gmax, float*& gden,
                   float*& grep, bf16*& AGG) -> size_t {
        size_t off = 0;
        auto alloc = [&](size_t sz) { size_t r = off; off = (off + sz + 255) & ~(size_t)255; return r; };
        size_t oH   = alloc((size_t)N_NODES * DIM * 2);
        size_t oAC  = alloc((size_t)N_NODES * DIM * 2);
        size_t oWL  = alloc((size_t)DIM * KSTACK * 2);
        size_t oRP  = alloc((size_t)(NKEY + 1) * 4);
        size_t oCU  = alloc((size_t)NKEY * 4);
        size_t oEI  = alloc((size_t)N_EDGES * 4);
        size_t oGA  = alloc((size_t)N_NODES * 4);
        size_t oGM  = alloc(256);
        size_t oGD  = alloc(256);
        size_t oGR  = alloc((size_t)NGR * DIM * 4);
        size_t oAG  = alloc((size_t)N_NODES * nc * DIM * 2);
        if (doAssign) {
            h_bf = (bf16*)(ws + oH);   ACCb = (bf16*)(ws + oAC);
            WstL = (bf16*)(ws + oWL);  rp2  = (int*)(ws + oRP);
            cur2 = (int*)(ws + oCU);   eidx = (int*)(ws + oEI);
            gate = (float*)(ws + oGA); gmax = (float*)(ws + oGM);
            gden = (float*)(ws + oGD); grep = (float*)(ws + oGR);
            AGG  = (bf16*)(ws + oAG);
        }
        return off;
    };

    bf16 *h_bf, *ACCb, *WstL, *AGG; int *rp2, *cur2, *eidx;
    float *gate, *gmax, *gden, *grep;
    bf16 *d0=nullptr,*d1=nullptr,*d2=nullptr,*d3=nullptr; int *d4=nullptr,*d5=nullptr,*d6=nullptr;
    float *d7=nullptr,*d8=nullptr,*d9=nullptr,*d10=nullptr;
    const bool big = ws_size >= lay(8, false, d0,d1,d2,d4,d5,d6,d7,d8,d9,d10,d3);
    const int nc = big ? 8 : 4;
    lay(nc, true, h_bf, ACCb, WstL, rp2, cur2, eidx, gate, gmax, gden, grep, AGG);

    // AGG-region overlays
    bf16* Xbf  = AGG;                                             // [N][800]
    bf16* WinT = (bf16*)((char*)AGG + (size_t)N_NODES * KIN * 2); // [768][800]
    bf16* G1   = AGG;                                             // [N][384] bf16 at gate time

    const int AGW = nc * DIM;

    // --- input projection (X/WIN overlay AGG; dead before gathers)
    tcast_k<<<dim3(25, 24), 256, 0, stream>>>(W_in, WinT, 784, DIM, KIN, KIN);
    concat_k<<<N_NODES, 256, 0, stream>>>(type_vec, code_vec, Xbf);
    gemm384<0><<<256, 512, 0, stream>>>(Xbf, KIN, KIN, Xbf, KIN, WinT, KIN, ACCb, DIM, KIN, 2);
    ln_gelu_k<<<N_NODES / 4, 256, 0, stream>>>(ACCb, b_in, ln_in_g, ln_in_b, h_bf);

    // --- (dst,type) CSR build
    hipMemsetAsync(cur2, 0, (size_t)NKEY * 4, stream);
    hist2_k<<<N_EDGES / 256, 256, 0, stream>>>(dst, etype, cur2);
    scan2_k<<<1, 1024, 0, stream>>>(cur2, rp2);
    place2_k<<<N_EDGES / 256, 256, 0, stream>>>(src, dst, etype, cur2, eidx);

    // --- RGCN layers
    for (int l = 0; l < 3; ++l) {
        wprep_l_k<<<dim3(24, 24, 9), 256, 0, stream>>>(
            W_rel + (size_t)l * 8 * DIM * DIM, W_loop + (size_t)l * DIM * DIM, WstL);
        if (nc == 8) {
            gather8<8><<<N_NODES / 4, 256, 0, stream>>>(h_bf, rp2, eidx, AGG, 0, AGW, 0);
            gemm384<0><<<256, 512, 0, stream>>>(
                h_bf, DIM, DIM, AGG, AGW, WstL, KSTACK, ACCb, DIM, KSTACK, 2);
        } else {
            gather8<4><<<N_NODES / 4, 256, 0, stream>>>(h_bf, rp2, eidx, AGG, 0, AGW, 0);
            gemm384<0><<<256, 512, 0, stream>>>(
                h_bf, DIM, DIM, AGG, AGW, WstL, KSTACK, ACCb, DIM, DIM + 4 * DIM, 2);
            gather8<4><<<N_NODES / 4, 256, 0, stream>>>(h_bf, rp2, eidx, AGG, 4, AGW, 0);
            gemm384<1><<<256, 512, 0, stream>>>(
                AGG, AGW, AGW, AGG, AGW, WstL + (size_t)DIM * 5, KSTACK, ACCb, DIM, 4 * DIM, 2);
        }
        ln_gelu_k<<<N_NODES / 4, 256, 0, stream>>>(ACCb, rgcn_bias + l * DIM, ln_g + l * DIM,
                                                   ln_b + l * DIM, h_bf);
    }

    // --- global attention pooling (G1/Wg1T overlay AGG region, AGG dead)
    bf16* Wg1T = (bf16*)((char*)AGG + 60 * 1024 * 1024);
    tcast_k<<<dim3(24, 12), 256, 0, stream>>>(Wg1, Wg1T, DIM, 384, DIM, DIM);
    gemm384<0><<<128, 512, 0, stream>>>(h_bf, DIM, DIM, h_bf, DIM, Wg1T, DIM, G1, 384, DIM, 1);
    gate_k<<<N_NODES / 4, 256, 0, stream>>>(G1, bg1, Wg2, bg2, gate);
    seg_stats_k<<<NGR, 256, 0, stream>>>(gate, node_graph, gmax, gden);
    pool_k<<<NGR, 768, 0, stream>>>(h_bf, gate, node_graph, gmax, gden, grep);

    // --- classifier head
    cls_k<<<NGR, 512, 0, stream>>>(grep, Wc1, bc1, ln_c_g, ln_c_b, Wc2, bc2, (float*)d_out);
}

// Round 13
// 2446.288 us; speedup vs baseline: 1.5101x; 1.0013x over previous
//
#include <hip/hip_runtime.h>
#include <hip/hip_bf16.h>

typedef __hip_bfloat16 bf16;
typedef __attribute__((ext_vector_type(8))) __bf16 bf16x8;
typedef __attribute__((ext_vector_type(4))) float f32x4;

#define N_NODES 32768
#define N_EDGES 262144
#define DIM 768
#define NGR 64
#define KIN 800     // 784 padded to 32
#define KSTACK 6912 // self(768) + 8*768
#define NKEY (N_NODES * 8)

#define GLOBAL_AS __attribute__((address_space(1)))
#define LDS_AS __attribute__((address_space(3)))

__device__ __forceinline__ float gelu_f(float x) {
    return 0.5f * x * (1.0f + erff(x * 0.70710678118654752f));
}
__device__ __forceinline__ float bfu(unsigned short v) {
    union { unsigned u; float f; } x; x.u = (unsigned)v << 16; return x.f;
}
__device__ __forceinline__ unsigned short fbf(float f) {
    bf16 t = __float2bfloat16(f); return *(unsigned short*)&t;
}

// ---------------------------------------------------------------------------
// Transpose + cast fp32 [I][O] -> bf16 [O][ostride], zero-pad i in [I,Ipad)
__global__ __launch_bounds__(256)
void tcast_k(const float* __restrict__ in, bf16* __restrict__ out, int I, int O,
             int Ipad, int ostride) {
    __shared__ float t[32][33];
    const int i0 = blockIdx.x * 32, o0 = blockIdx.y * 32;
    const int tx = threadIdx.x & 31, ty = threadIdx.x >> 5;
#pragma unroll
    for (int q = 0; q < 4; ++q) {
        int i = i0 + ty + q * 8, o = o0 + tx;
        t[ty + q * 8][tx] = (i < I) ? in[(size_t)i * O + o] : 0.0f;
    }
    __syncthreads();
#pragma unroll
    for (int q = 0; q < 4; ++q) {
        int o = o0 + ty + q * 8, i = i0 + tx;
        if (i < Ipad) out[(size_t)o * ostride + i] = __float2bfloat16(t[tx][ty + q * 8]);
    }
}

// ---------------------------------------------------------------------------
// Per-layer weights -> WstL[768 out][6912 K], K order: [self | r0..r7]. grid(24,24,9)
__global__ __launch_bounds__(256)
void wprep_l_k(const float* __restrict__ Wrel_l, const float* __restrict__ Wloop_l,
               bf16* __restrict__ WstL) {
    __shared__ float t[32][33];
    const int q = blockIdx.z;
    const float* in = (q < 8) ? Wrel_l + (size_t)q * DIM * DIM : Wloop_l;
    bf16* out = WstL + (q < 8 ? (q + 1) * DIM : 0);
    const int i0 = blockIdx.x * 32, o0 = blockIdx.y * 32;
    const int tx = threadIdx.x & 31, ty = threadIdx.x >> 5;
#pragma unroll
    for (int qq = 0; qq < 4; ++qq)
        t[ty + qq * 8][tx] = in[(size_t)(i0 + ty + qq * 8) * DIM + o0 + tx];
    __syncthreads();
#pragma unroll
    for (int qq = 0; qq < 4; ++qq)
        out[(size_t)(o0 + ty + qq * 8) * KSTACK + i0 + tx] =
            __float2bfloat16(t[tx][ty + qq * 8]);
}

// ---------------------------------------------------------------------------
__global__ __launch_bounds__(256)
void concat_k(const float* __restrict__ tv, const float* __restrict__ cv, bf16* __restrict__ X) {
    const int n = blockIdx.x;
    for (int c = threadIdx.x; c < KIN; c += 256) {
        float v = 0.0f;
        if (c < 16) v = tv[(size_t)n * 16 + c];
        else if (c < 784) v = cv[(size_t)n * DIM + (c - 16)];
        X[(size_t)n * KIN + c] = __float2bfloat16(v);
    }
}

// ---------------------------------------------------------------------------
// CSR build over key = dst*8 + type. deg aliased into cur.
__global__ __launch_bounds__(256)
void hist2_k(const int* __restrict__ dst, const int* __restrict__ et, int* __restrict__ cur) {
    int e = blockIdx.x * 256 + threadIdx.x;
    if (e < N_EDGES) atomicAdd(&cur[dst[e] * 8 + et[e]], 1);
}

__global__ __launch_bounds__(1024)
void scan2_k(int* __restrict__ cur, int* __restrict__ rp) {
    __shared__ int part[1024];
    const int t = threadIdx.x;
    const int base_i = t * 256;
    int s = 0;
    for (int i = 0; i < 256; ++i) s += cur[base_i + i];
    part[t] = s; __syncthreads();
    for (int st = 1; st < 1024; st <<= 1) {
        int v = (t >= st) ? part[t - st] : 0;
        __syncthreads();
        part[t] += v;
        __syncthreads();
    }
    int run = part[t] - s;
    for (int i = 0; i < 256; ++i) {
        int d = cur[base_i + i];
        rp[base_i + i] = run; cur[base_i + i] = run;
        run += d;
    }
    if (t == 1023) rp[NKEY] = run;
}

__global__ __launch_bounds__(256)
void place2_k(const int* __restrict__ src, const int* __restrict__ dst,
              const int* __restrict__ et, int* __restrict__ cur,
              int* __restrict__ eidx) {
    int e = blockIdx.x * 256 + threadIdx.x;
    if (e >= N_EDGES) return;
    int pos = atomicAdd(&cur[dst[e] * 8 + et[e]], 1);
    eidx[pos] = (et[e] << 16) | src[e];
}

// ---------------------------------------------------------------------------
// Single-pass gather: one scan over node's FULL edge range (8 relations are
// contiguous in the (dst,type)-sorted CSR). sel is wave-uniform (wave per
// node) -> the switch is a uniform branch, no divergence. 8 static 12-reg
// accumulator banks (rule #20: no runtime indexing).
__global__ __launch_bounds__(256)
void gather1p(const bf16* __restrict__ h, const int* __restrict__ rp2,
              const int* __restrict__ eidx, bf16* __restrict__ AGG, int ostride) {
    const int wave = threadIdx.x >> 6, lane = threadIdx.x & 63;
    const int n = blockIdx.x * 4 + wave;
    const int c0 = 4 * lane;
    const int start = rp2[n * 8], end = rp2[n * 8 + 8];
    float f0[12] = {}, f1[12] = {}, f2[12] = {}, f3[12] = {};
    float f4[12] = {}, f5[12] = {}, f6[12] = {}, f7[12] = {};
    for (int t = start; t < end; ++t) {
        const int pk = eidx[t];
        const int sel = pk >> 16;
        const unsigned short* hs = (const unsigned short*)&h[(size_t)(pk & 0xffff) * DIM];
        ushort4 u0 = *(const ushort4*)&hs[c0];
        ushort4 u1 = *(const ushort4*)&hs[c0 + 256];
        ushort4 u2 = *(const ushort4*)&hs[c0 + 512];
#define ADDE(F) { F[0]+=bfu(u0.x); F[1]+=bfu(u0.y); F[2]+=bfu(u0.z); F[3]+=bfu(u0.w); \
                  F[4]+=bfu(u1.x); F[5]+=bfu(u1.y); F[6]+=bfu(u1.z); F[7]+=bfu(u1.w); \
                  F[8]+=bfu(u2.x); F[9]+=bfu(u2.y); F[10]+=bfu(u2.z); F[11]+=bfu(u2.w); }
        switch (sel) {
            case 0: ADDE(f0) break;
            case 1: ADDE(f1) break;
            case 2: ADDE(f2) break;
            case 3: ADDE(f3) break;
            case 4: ADDE(f4) break;
            case 5: ADDE(f5) break;
            case 6: ADDE(f6) break;
            default: ADDE(f7) break;
        }
#undef ADDE
    }
    unsigned short* outrow = (unsigned short*)&AGG[(size_t)n * ostride];
#define STE(F, S) _Pragma("unroll") for (int j = 0; j < 3; ++j) { ushort4 o; \
        o.x = fbf(F[4*j+0]); o.y = fbf(F[4*j+1]); o.z = fbf(F[4*j+2]); o.w = fbf(F[4*j+3]); \
        *(ushort4*)&outrow[(S) * DIM + c0 + j * 256] = o; }
    STE(f0, 0) STE(f1, 1) STE(f2, 2) STE(f3, 3)
    STE(f4, 4) STE(f5, 5) STE(f6, 6) STE(f7, 7)
#undef STE
}

// ---------------------------------------------------------------------------
// Fallback gather (nc=4 path)
template <int NC>
__global__ __launch_bounds__(256)
void gather8(const bf16* __restrict__ h, const int* __restrict__ rp2,
             const int* __restrict__ eidx, bf16* __restrict__ AGG,
             int rbase, int ostride, int colbase) {
    const int wave = threadIdx.x >> 6, lane = threadIdx.x & 63;
    const int n = blockIdx.x * 4 + wave;
    const int c0 = 4 * lane;
    unsigned short* outrow = (unsigned short*)&AGG[(size_t)n * ostride + colbase];
    const int* bp = &rp2[n * 8 + rbase];
    for (int sel = 0; sel < NC; ++sel) {
        const int s = bp[sel], e = bp[sel + 1];
        float f[12];
#pragma unroll
        for (int j = 0; j < 12; ++j) f[j] = 0.f;
        for (int t = s; t < e; ++t) {
            const int srcn = eidx[t] & 0xffff;
            const unsigned short* hs = (const unsigned short*)&h[(size_t)srcn * DIM];
#pragma unroll
            for (int j = 0; j < 3; ++j) {
                ushort4 u = *(const ushort4*)&hs[c0 + j * 256];
                f[4 * j + 0] += bfu(u.x); f[4 * j + 1] += bfu(u.y);
                f[4 * j + 2] += bfu(u.z); f[4 * j + 3] += bfu(u.w);
            }
        }
#pragma unroll
        for (int j = 0; j < 3; ++j) {
            ushort4 o;
            o.x = fbf(f[4 * j + 0]); o.y = fbf(f[4 * j + 1]);
            o.z = fbf(f[4 * j + 2]); o.w = fbf(f[4 * j + 3]);
            *(ushort4*)&outrow[sel * DIM + c0 + j * 256] = o;
        }
    }
}

// ---------------------------------------------------------------------------
// gemm_ln: h[M,768](bf16, IN-PLACE safe) = gelu(LN(A @ BT^T + bias)) with
// per-row LayerNorm fused into the epilogue. BM=128, BN=768 (=Nn, nbx=1: each
// block owns complete rows -> row-LN is block-local; A rows read only by the
// owning block so writing h in place is race-free). BK=32, 8 waves (2 row x
// 4 col), acc[4][12] = 192 VGPR (same as gemm384). 2-deep LDS pipeline
// (56KB/buf + 4KB reduce = 116KB), counted vmcnt(7/0); proven 0-conflict
// swizzle; XCD-chunked block swizzle (grid 256).
__global__ __launch_bounds__(512, 2)
void gemm_ln(const bf16* __restrict__ A1, int S1, int K1,
             const bf16* __restrict__ A2, int S2,
             const bf16* __restrict__ BT, int ldb,
             const float* __restrict__ bias, const float* __restrict__ g,
             const float* __restrict__ b, bf16* __restrict__ OUT, int Ktot) {
    __shared__ __align__(16) unsigned short lA[2][128 * 32];
    __shared__ __align__(16) unsigned short lB[2][768 * 32];
    __shared__ float lred[128][8];
    const int nblk = gridDim.x, qx = nblk >> 3, bid = blockIdx.x;
    const int wgid = (bid & 7) * qx + (bid >> 3);
    const int bm = wgid * 128;
    const int tid = threadIdx.x;
    const int wave = tid >> 6, lane = tid & 63;
    const int wr = wave >> 2, wc = wave & 3;
    const int l15 = lane & 15, lg = lane >> 4;
    const int swz = (lg ^ ((l15 >> 1) & 3)) * 8;

    f32x4 acc[4][12] = {};
    const int nkt = Ktot >> 5;

    auto stage = [&](int t, int buf) {
        const int k0 = t * 32;
        const bf16* Ab; int koff, stA;
        if (k0 < K1) { Ab = A1; koff = k0; stA = S1; }
        else         { Ab = A2; koff = k0 - K1; stA = S2; }
        {   // A: 128x32 = 512 chunks, 1/thread
            const int r = tid >> 2, s = tid & 3;
            const int sc = (s ^ ((r >> 1) & 3)) * 8;
            const bf16* ga = Ab + (size_t)(bm + r) * stA + koff + sc;
            __builtin_amdgcn_global_load_lds((const GLOBAL_AS void*)ga,
                (LDS_AS void*)&lA[buf][(wave * 64) * 8], 16, 0, 0);
        }
#pragma unroll
        for (int u = 0; u < 6; ++u) {   // B: 768x32 = 3072 chunks, 6/thread
            const int c = u * 512 + tid;
            const int r = c >> 2, s = c & 3;
            const int sc = (s ^ ((r >> 1) & 3)) * 8;
            const bf16* gb = BT + (size_t)r * ldb + k0 + sc;
            __builtin_amdgcn_global_load_lds((const GLOBAL_AS void*)gb,
                (LDS_AS void*)&lB[buf][((u * 8 + wave) * 64) * 8], 16, 0, 0);
        }
    };

    stage(0, 0);

    for (int t = 0; t < nkt; ++t) {
        const int rb = t & 1;
        if (t + 1 < nkt) {
            stage(t + 1, rb ^ 1);
            asm volatile("s_waitcnt vmcnt(7)" ::: "memory");
        } else {
            asm volatile("s_waitcnt vmcnt(0)" ::: "memory");
        }
        __builtin_amdgcn_s_barrier();
        __builtin_amdgcn_sched_barrier(0);

        bf16x8 af[4];
#pragma unroll
        for (int mi = 0; mi < 4; ++mi) {
            const int r = wr * 64 + mi * 16 + l15;
            af[mi] = *reinterpret_cast<const bf16x8*>(&lA[rb][r * 32 + swz]);
        }
        __builtin_amdgcn_s_setprio(1);
#pragma unroll
        for (int ni = 0; ni < 12; ++ni) {
            const int r = wc * 192 + ni * 16 + l15;
            bf16x8 bq = *reinterpret_cast<const bf16x8*>(&lB[rb][r * 32 + swz]);
#pragma unroll
            for (int mi = 0; mi < 4; ++mi)
                acc[mi][ni] = __builtin_amdgcn_mfma_f32_16x16x32_bf16(af[mi], bq, acc[mi][ni], 0, 0, 0);
        }
        __builtin_amdgcn_s_setprio(0);
        __builtin_amdgcn_sched_barrier(0);
        __builtin_amdgcn_s_barrier();
    }

    // ---- fused bias + LayerNorm + GELU epilogue
    float biasv[12], gv[12], bvv[12];
#pragma unroll
    for (int ni = 0; ni < 12; ++ni) {
        const int col = wc * 192 + ni * 16 + l15;
        biasv[ni] = bias[col]; gv[ni] = g[col]; bvv[ni] = b[col];
    }
#pragma unroll
    for (int mi = 0; mi < 4; ++mi)
#pragma unroll
        for (int ni = 0; ni < 12; ++ni)
#pragma unroll
            for (int i = 0; i < 4; ++i)
                acc[mi][ni][i] += biasv[ni];
    // per-row partial stats (wave covers 192 cols of each of its 16 rows)
#pragma unroll
    for (int mi = 0; mi < 4; ++mi)
#pragma unroll
        for (int i = 0; i < 4; ++i) {
            float s = 0.f, ss = 0.f;
#pragma unroll
            for (int ni = 0; ni < 12; ++ni) {
                float v = acc[mi][ni][i];
                s += v; ss += v * v;
            }
#pragma unroll
            for (int m = 1; m < 16; m <<= 1) {
                s += __shfl_xor(s, m, 64); ss += __shfl_xor(ss, m, 64);
            }
            if (l15 == 0) {
                const int rloc = wr * 64 + mi * 16 + lg * 4 + i;
                lred[rloc][wc] = s; lred[rloc][4 + wc] = ss;
            }
        }
    __syncthreads();
    unsigned short* O = (unsigned short*)OUT;
#pragma unroll
    for (int mi = 0; mi < 4; ++mi)
#pragma unroll
        for (int i = 0; i < 4; ++i) {
            const int rloc = wr * 64 + mi * 16 + lg * 4 + i;
            const float s = lred[rloc][0] + lred[rloc][1] + lred[rloc][2] + lred[rloc][3];
            const float q = lred[rloc][4] + lred[rloc][5] + lred[rloc][6] + lred[rloc][7];
            const float mean = s * (1.f / DIM);
            const float var = q * (1.f / DIM) - mean * mean;
            const float rstd = rsqrtf(var + 1e-5f);
            const size_t rowoff = (size_t)(bm + rloc) * DIM;
#pragma unroll
            for (int ni = 0; ni < 12; ++ni) {
                const int col = wc * 192 + ni * 16 + l15;
                const float y = (acc[mi][ni][i] - mean) * rstd * gv[ni] + bvv[ni];
                O[rowoff + col] = fbf(gelu_f(y));
            }
        }
}

// ---------------------------------------------------------------------------
// gemm384 (gate GEMM + nc=4 fallback): C[M,Nn](bf16) =/+= A @ BT^T.
// BM=256, BN=384, 3-deep counted-vmcnt pipeline (round-12 proven).
template <int MODE>
__global__ __launch_bounds__(512, 2)
void gemm384(const bf16* __restrict__ A1, int S1, int K1,
             const bf16* __restrict__ A2, int S2,
             const bf16* __restrict__ BT, int ldb,
             bf16* __restrict__ OUT, int Nn, int Ktot, int nbx) {
    __shared__ __align__(16) unsigned short lA[3][256 * 32];
    __shared__ __align__(16) unsigned short lB[3][384 * 32];
    const int nblk = gridDim.x, qx = nblk >> 3, bid = blockIdx.x;
    const int wgid = (bid & 7) * qx + (bid >> 3);
    const int bx = wgid % nbx, by = wgid / nbx;
    const int bn = bx * 384, bm = by * 256;
    const int tid = threadIdx.x;
    const int wave = tid >> 6, lane = tid & 63;
    const int wr = wave >> 1, wc = wave & 1;
    const int l15 = lane & 15, lg = lane >> 4;
    const int swz = (lg ^ ((l15 >> 1) & 3)) * 8;

    f32x4 acc[4][12] = {};
    const int nkt = Ktot >> 5;

    auto stage = [&](int t, int buf) {
        const int k0 = t * 32;
        const bf16* Ab; int koff, stA;
        if (k0 < K1) { Ab = A1; koff = k0; stA = S1; }
        else         { Ab = A2; koff = k0 - K1; stA = S2; }
#pragma unroll
        for (int u = 0; u < 2; ++u) {
            const int c = u * 512 + tid;
            const int r = c >> 2, s = c & 3;
            const int sc = (s ^ ((r >> 1) & 3)) * 8;
            const bf16* ga = Ab + (size_t)(bm + r) * stA + koff + sc;
            __builtin_amdgcn_global_load_lds((const GLOBAL_AS void*)ga,
                (LDS_AS void*)&lA[buf][(u * 512 + wave * 64) * 8], 16, 0, 0);
        }
#pragma unroll
        for (int u = 0; u < 3; ++u) {
            const int c = u * 512 + tid;
            const int r = c >> 2, s = c & 3;
            const int sc = (s ^ ((r >> 1) & 3)) * 8;
            const bf16* gb = BT + (size_t)(bn + r) * ldb + k0 + sc;
            __builtin_amdgcn_global_load_lds((const GLOBAL_AS void*)gb,
                (LDS_AS void*)&lB[buf][(u * 512 + wave * 64) * 8], 16, 0, 0);
        }
    };

    stage(0, 0);
    if (nkt > 1) stage(1, 1);

    int rb = 0;
    for (int t = 0; t < nkt; ++t) {
        if (t + 2 < nkt) {
            int sb = rb + 2; if (sb >= 3) sb -= 3;
            stage(t + 2, sb);
            asm volatile("s_waitcnt vmcnt(10)" ::: "memory");
        } else if (t + 1 < nkt) {
            asm volatile("s_waitcnt vmcnt(5)" ::: "memory");
        } else {
            asm volatile("s_waitcnt vmcnt(0)" ::: "memory");
        }
        __builtin_amdgcn_s_barrier();
        __builtin_amdgcn_sched_barrier(0);

        bf16x8 af[4];
#pragma unroll
        for (int mi = 0; mi < 4; ++mi) {
            const int r = wr * 64 + mi * 16 + l15;
            af[mi] = *reinterpret_cast<const bf16x8*>(&lA[rb][r * 32 + swz]);
        }
        __builtin_amdgcn_s_setprio(1);
#pragma unroll
        for (int ni = 0; ni < 12; ++ni) {
            const int r = wc * 192 + ni * 16 + l15;
            bf16x8 bq = *reinterpret_cast<const bf16x8*>(&lB[rb][r * 32 + swz]);
#pragma unroll
            for (int mi = 0; mi < 4; ++mi)
                acc[mi][ni] = __builtin_amdgcn_mfma_f32_16x16x32_bf16(af[mi], bq, acc[mi][ni], 0, 0, 0);
        }
        __builtin_amdgcn_s_setprio(0);
        __builtin_amdgcn_sched_barrier(0);
        __builtin_amdgcn_s_barrier();

        rb = (rb == 2) ? 0 : rb + 1;
    }

    unsigned short* O = (unsigned short*)OUT;
#pragma unroll
    for (int mi = 0; mi < 4; ++mi)
#pragma unroll
        for (int ni = 0; ni < 12; ++ni) {
            const int r0 = bm + wr * 64 + mi * 16 + lg * 4;
            const int c0 = bn + wc * 192 + ni * 16 + l15;
#pragma unroll
            for (int i = 0; i < 4; ++i) {
                size_t idx = (size_t)(r0 + i) * Nn + c0;
                float v = acc[mi][ni][i];
                if (MODE == 1) v += bfu(O[idx]);
                O[idx] = fbf(v);
            }
        }
}

// ---------------------------------------------------------------------------
// Fallback: bias + LN + GELU over bf16 partials; wave per row.
__global__ __launch_bounds__(256)
void ln_gelu_k(const bf16* __restrict__ ACCb, const float* __restrict__ bias,
               const float* __restrict__ g, const float* __restrict__ b,
               bf16* __restrict__ hout) {
    const int wave = threadIdx.x >> 6, lane = threadIdx.x & 63;
    const int n = blockIdx.x * 4 + wave;
    const unsigned short* Ab = (const unsigned short*)ACCb;
    float x[12];
    float s = 0.f, ss = 0.f;
#pragma unroll
    for (int j = 0; j < 12; ++j) {
        int c = lane + j * 64;
        x[j] = bfu(Ab[(size_t)n * DIM + c]) + bias[c];
        s += x[j]; ss += x[j] * x[j];
    }
#pragma unroll
    for (int m = 1; m < 64; m <<= 1) { s += __shfl_xor(s, m, 64); ss += __shfl_xor(ss, m, 64); }
    const float mean = s * (1.f / DIM);
    const float var = ss * (1.f / DIM) - mean * mean;
    const float rstd = rsqrtf(var + 1e-5f);
#pragma unroll
    for (int j = 0; j < 12; ++j) {
        int c = lane + j * 64;
        float y = (x[j] - mean) * rstd * g[c] + b[c];
        hout[(size_t)n * DIM + c] = __float2bfloat16(gelu_f(y));
    }
}

// ---------------------------------------------------------------------------
__global__ __launch_bounds__(256)
void gate_k(const bf16* __restrict__ G1, const float* __restrict__ bg1,
            const float* __restrict__ Wg2, const float* __restrict__ bg2,
            float* __restrict__ gate) {
    const int wave = threadIdx.x >> 6, lane = threadIdx.x & 63;
    const int n = blockIdx.x * 4 + wave;
    const unsigned short* G = (const unsigned short*)G1;
    float acc = 0.f;
#pragma unroll
    for (int j = 0; j < 6; ++j) {
        int c = lane + j * 64;
        float xv = bfu(G[(size_t)n * 384 + c]) + bg1[c];
        acc += gelu_f(xv) * Wg2[c];
    }
#pragma unroll
    for (int m = 1; m < 64; m <<= 1) acc += __shfl_xor(acc, m, 64);
    if (lane == 0) gate[n] = acc + bg2[0];
}

// ---------------------------------------------------------------------------
__device__ __forceinline__ int lower_bound_ng(const int* ng, int key) {
    int lo = 0, hi = N_NODES;
    while (lo < hi) { int mid = (lo + hi) >> 1; if (ng[mid] < key) lo = mid + 1; else hi = mid; }
    return lo;
}

__global__ __launch_bounds__(256)
void seg_stats_k(const float* __restrict__ gate, const int* __restrict__ ng,
                 float* __restrict__ gmax, float* __restrict__ gden) {
    __shared__ float red[256];
    const int b = blockIdx.x, t = threadIdx.x;
    const int start = lower_bound_ng(ng, b), end = lower_bound_ng(ng, b + 1);
    float m = -1e30f;
    for (int n = start + t; n < end; n += 256) m = fmaxf(m, gate[n]);
    red[t] = m; __syncthreads();
    for (int s = 128; s > 0; s >>= 1) { if (t < s) red[t] = fmaxf(red[t], red[t + s]); __syncthreads(); }
    const float gm = red[0]; __syncthreads();
    float ssum = 0.f;
    for (int n = start + t; n < end; n += 256) ssum += expf(gate[n] - gm);
    red[t] = ssum; __syncthreads();
    for (int s = 128; s > 0; s >>= 1) { if (t < s) red[t] += red[t + s]; __syncthreads(); }
    if (t == 0) { gmax[b] = gm; gden[b] = fmaxf(red[0], 1e-30f); }
}

__global__ __launch_bounds__(768)
void pool_k(const bf16* __restrict__ h, const float* __restrict__ gate,
            const int* __restrict__ ng, const float* __restrict__ gmax,
            const float* __restrict__ gden, float* __restrict__ grep) {
    const int b = blockIdx.x, c = threadIdx.x;
    const int start = lower_bound_ng(ng, b), end = lower_bound_ng(ng, b + 1);
    const float gm = gmax[b], inv = 1.0f / gden[b];
    const unsigned short* hv = (const unsigned short*)h;
    float a0 = 0.f, a1 = 0.f;
    int n = start;
    for (; n + 1 < end; n += 2) {
        float w0 = expf(gate[n] - gm) * inv;
        float w1 = expf(gate[n + 1] - gm) * inv;
        a0 += w0 * bfu(hv[(size_t)n * DIM + c]);
        a1 += w1 * bfu(hv[(size_t)(n + 1) * DIM + c]);
    }
    if (n < end) a0 += expf(gate[n] - gm) * inv * bfu(hv[(size_t)n * DIM + c]);
    grep[(size_t)b * DIM + c] = a0 + a1;
}

// ---------------------------------------------------------------------------
__global__ __launch_bounds__(512)
void cls_k(const float* __restrict__ grep, const float* __restrict__ Wc1,
           const float* __restrict__ bc1, const float* __restrict__ lng,
           const float* __restrict__ lnb, const float* __restrict__ Wc2,
           const float* __restrict__ bc2, float* __restrict__ out) {
    __shared__ float gr[DIM];
    __shared__ float red[512];
    const int b = blockIdx.x, j = threadIdx.x;
    for (int c = j; c < DIM; c += 512) gr[c] = grep[(size_t)b * DIM + c];
    __syncthreads();
    float a = bc1[j];
#pragma unroll 4
    for (int k = 0; k < DIM; ++k) a = fmaf(gr[k], Wc1[(size_t)k * 512 + j], a);
    red[j] = a; __syncthreads();
    for (int s = 256; s > 0; s >>= 1) { if (j < s) red[j] += red[j + s]; __syncthreads(); }
    const float mean = red[0] * (1.f / 512.f);
    __syncthreads();
    red[j] = (a - mean) * (a - mean); __syncthreads();
    for (int s = 256; s > 0; s >>= 1) { if (j < s) red[j] += red[j + s]; __syncthreads(); }
    const float rstd = rsqrtf(red[0] * (1.f / 512.f) + 1e-5f);
    __syncthreads();
    const float z = gelu_f((a - mean) * rstd * lng[j] + lnb[j]);
    red[j] = z * Wc2[2 * j + 0]; __syncthreads();
    for (int s = 256; s > 0; s >>= 1) { if (j < s) red[j] += red[j + s]; __syncthreads(); }
    const float l0 = red[0] + bc2[0];
    __syncthreads();
    red[j] = z * Wc2[2 * j + 1]; __syncthreads();
    for (int s = 256; s > 0; s >>= 1) { if (j < s) red[j] += red[j + s]; __syncthreads(); }
    if (j == 0) {
        const float l1 = red[0] + bc2[1];
        const float mx = fmaxf(l0, l1);
        const float lse = mx + logf(expf(l0 - mx) + expf(l1 - mx));
        out[2 * b + 0] = l0 - lse;
        out[2 * b + 1] = l1 - lse;
    }
}

// ---------------------------------------------------------------------------
extern "C" void kernel_launch(void* const* d_in, const int* in_sizes, int n_in,
                              void* d_out, int out_size, void* d_ws, size_t ws_size,
                              hipStream_t stream) {
    const float* type_vec = (const float*)d_in[0];
    const float* code_vec = (const float*)d_in[1];
    const float* W_in     = (const float*)d_in[2];
    const float* b_in     = (const float*)d_in[3];
    const float* ln_in_g  = (const float*)d_in[4];
    const float* ln_in_b  = (const float*)d_in[5];
    const float* W_rel    = (const float*)d_in[6];
    const float* W_loop   = (const float*)d_in[7];
    const float* rgcn_bias= (const float*)d_in[8];
    const float* ln_g     = (const float*)d_in[9];
    const float* ln_b     = (const float*)d_in[10];
    const float* Wg1      = (const float*)d_in[11];
    const float* bg1      = (const float*)d_in[12];
    const float* Wg2      = (const float*)d_in[13];
    const float* bg2      = (const float*)d_in[14];
    const float* Wc1      = (const float*)d_in[15];
    const float* bc1      = (const float*)d_in[16];
    const float* ln_c_g   = (const float*)d_in[17];
    const float* ln_c_b   = (const float*)d_in[18];
    const float* Wc2      = (const float*)d_in[19];
    const float* bc2      = (const float*)d_in[20];
    const int* src        = (const int*)d_in[21];
    const int* dst        = (const int*)d_in[22];
    const int* etype      = (const int*)d_in[23];
    const int* node_graph = (const int*)d_in[24];

    char* ws = (char*)d_ws;

    auto lay = [&](int nc, bool doAssign,
                   bf16*& h_bf, bf16*& ACCb, bf16*& WstL, int*& rp2, int*& cur2,
                   int*& eidx, float*& gate, float*& gmax, float*& gden,
                   float*& grep, bf16*& AGG) -> size_t {
        size_t off = 0;
        auto alloc = [&](size_t sz) { size_t r = off; off = (off + sz + 255) & ~(size_t)255; return r; };
        size_t oH   = alloc((size_t)N_NODES * DIM * 2);
        size_t oAC  = alloc((size_t)N_NODES * DIM * 2);
        size_t oWL  = alloc((size_t)DIM * KSTACK * 2);
        size_t oRP  = alloc((size_t)(NKEY + 1) * 4);
        size_t oCU  = alloc((size_t)NKEY * 4);
        size_t oEI  = alloc((size_t)N_EDGES * 4);
        size_t oGA  = alloc((size_t)N_NODES * 4);
        size_t oGM  = alloc(256);
        size_t oGD  = alloc(256);
        size_t oGR  = alloc((size_t)NGR * DIM * 4);
        size_t oAG  = alloc((size_t)N_NODES * nc * DIM * 2);
        if (doAssign) {
            h_bf = (bf16*)(ws + oH);   ACCb = (bf16*)(ws + oAC);
            WstL = (bf16*)(ws + oWL);  rp2  = (int*)(ws + oRP);
            cur2 = (int*)(ws + oCU);   eidx = (int*)(ws + oEI);
            gate = (float*)(ws + oGA); gmax = (float*)(ws + oGM);
            gden = (float*)(ws + oGD); grep = (float*)(ws + oGR);
            AGG  = (bf16*)(ws + oAG);
        }
        return off;
    };

    bf16 *h_bf, *ACCb, *WstL, *AGG; int *rp2, *cur2, *eidx;
    float *gate, *gmax, *gden, *grep;
    bf16 *d0=nullptr,*d1=nullptr,*d2=nullptr,*d3=nullptr; int *d4=nullptr,*d5=nullptr,*d6=nullptr;
    float *d7=nullptr,*d8=nullptr,*d9=nullptr,*d10=nullptr;
    const bool big = ws_size >= lay(8, false, d0,d1,d2,d4,d5,d6,d7,d8,d9,d10,d3);
    const int nc = big ? 8 : 4;
    lay(nc, true, h_bf, ACCb, WstL, rp2, cur2, eidx, gate, gmax, gden, grep, AGG);

    // AGG-region overlays
    bf16* Xbf  = AGG;                                             // [N][800]
    bf16* WinT = (bf16*)((char*)AGG + (size_t)N_NODES * KIN * 2); // [768][800]
    bf16* G1   = AGG;                                             // [N][384] bf16 at gate time

    const int AGW = nc * DIM;

    // --- input projection (X/WIN overlay AGG; dead before gathers)
    tcast_k<<<dim3(25, 24), 256, 0, stream>>>(W_in, WinT, 784, DIM, KIN, KIN);
    concat_k<<<N_NODES, 256, 0, stream>>>(type_vec, code_vec, Xbf);
    if (big) {
        gemm_ln<<<256, 512, 0, stream>>>(Xbf, KIN, KIN, Xbf, KIN, WinT, KIN,
                                         b_in, ln_in_g, ln_in_b, h_bf, KIN);
    } else {
        gemm384<0><<<256, 512, 0, stream>>>(Xbf, KIN, KIN, Xbf, KIN, WinT, KIN, ACCb, DIM, KIN, 2);
        ln_gelu_k<<<N_NODES / 4, 256, 0, stream>>>(ACCb, b_in, ln_in_g, ln_in_b, h_bf);
    }

    // --- (dst,type) CSR build
    hipMemsetAsync(cur2, 0, (size_t)NKEY * 4, stream);
    hist2_k<<<N_EDGES / 256, 256, 0, stream>>>(dst, etype, cur2);
    scan2_k<<<1, 1024, 0, stream>>>(cur2, rp2);
    place2_k<<<N_EDGES / 256, 256, 0, stream>>>(src, dst, etype, cur2, eidx);

    // --- RGCN layers
    for (int l = 0; l < 3; ++l) {
        wprep_l_k<<<dim3(24, 24, 9), 256, 0, stream>>>(
            W_rel + (size_t)l * 8 * DIM * DIM, W_loop + (size_t)l * DIM * DIM, WstL);
        if (nc == 8) {
            gather1p<<<N_NODES / 4, 256, 0, stream>>>(h_bf, rp2, eidx, AGG, AGW);
            gemm_ln<<<256, 512, 0, stream>>>(h_bf, DIM, DIM, AGG, AGW, WstL, KSTACK,
                                             rgcn_bias + l * DIM, ln_g + l * DIM,
                                             ln_b + l * DIM, h_bf, KSTACK);
        } else {
            gather8<4><<<N_NODES / 4, 256, 0, stream>>>(h_bf, rp2, eidx, AGG, 0, AGW, 0);
            gemm384<0><<<256, 512, 0, stream>>>(
                h_bf, DIM, DIM, AGG, AGW, WstL, KSTACK, ACCb, DIM, DIM + 4 * DIM, 2);
            gather8<4><<<N_NODES / 4, 256, 0, stream>>>(h_bf, rp2, eidx, AGG, 4, AGW, 0);
            gemm384<1><<<256, 512, 0, stream>>>(
                AGG, AGW, AGW, AGG, AGW, WstL + (size_t)DIM * 5, KSTACK, ACCb, DIM, 4 * DIM, 2);
            ln_gelu_k<<<N_NODES / 4, 256, 0, stream>>>(ACCb, rgcn_bias + l * DIM, ln_g + l * DIM,
                                                       ln_b + l * DIM, h_bf);
        }
    }

    // --- global attention pooling (G1/Wg1T overlay AGG region, AGG dead)
    bf16* Wg1T = (bf16*)((char*)AGG + 60 * 1024 * 1024);
    tcast_k<<<dim3(24, 12), 256, 0, stream>>>(Wg1, Wg1T, DIM, 384, DIM, DIM);
    gemm384<0><<<128, 512, 0, stream>>>(h_bf, DIM, DIM, h_bf, DIM, Wg1T, DIM, G1, 384, DIM, 1);
    gate_k<<<N_NODES / 4, 256, 0, stream>>>(G1, bg1, Wg2, bg2, gate);
    seg_stats_k<<<NGR, 256, 0, stream>>>(gate, node_graph, gmax, gden);
    pool_k<<<NGR, 768, 0, stream>>>(h_bf, gate, node_graph, gmax, gden, grep);

    // --- classifier head
    cls_k<<<NGR, 512, 0, stream>>>(grep, Wc1, bc1, ln_c_g, ln_c_b, Wc2, bc2, (float*)d_out);
}